// Round 2
// baseline (402.932 us; speedup 1.0000x reference)
//
#include <hip/hip_runtime.h>

// Problem constants
#define DM 4096   // d_model
#define DSZ 64    // d_state
#define NE 1024   // num evicted
#define SQ 2048   // seq len
#define NB 4      // batch

typedef __attribute__((ext_vector_type(8))) short bf16x8;
typedef __attribute__((ext_vector_type(4))) float f32x4;

__device__ __forceinline__ unsigned f2bf(float f) {
  union { float f; unsigned u; } v; v.f = f;
  return (v.u + 0x7fffu + ((v.u >> 16) & 1u)) >> 16;  // RNE fp32->bf16
}
__device__ __forceinline__ unsigned pack2(float lo, float hi) {
  return f2bf(lo) | (f2bf(hi) << 16);
}

// ---------------------------------------------------------------------------
// Kcvt_ev: ev_bf = bf16(evicted); fused summary[b][d] = mean_n evicted[b][n][d].
// Grid 512 = b(4) x dsl(8, 512 d each) x rgrp(16, 64 rows each). Block 256 = 4 waves.
// Wave w handles rows rgrp*64 + it*4 + w; lane handles d = dsl*512 + lane*8.
// ---------------------------------------------------------------------------
__launch_bounds__(256)
__global__ void k_cvt_ev(const float* __restrict__ ev, unsigned short* __restrict__ evb,
                         float* __restrict__ summary) {
  __shared__ float sred[4][512];
  const int bid = blockIdx.x;
  const int dsl = bid & 7, rgrp = (bid >> 3) & 15, b = bid >> 7;
  const int t = threadIdx.x;
  const int w = t >> 6, lane = t & 63;
  const int d = dsl * 512 + lane * 8;
  const size_t base = ((size_t)(b * NE + rgrp * 64 + w)) * DM + d;
  float s0=0,s1=0,s2=0,s3=0,s4=0,s5=0,s6=0,s7=0;
#pragma unroll 4
  for (int it = 0; it < 16; ++it) {
    const float* p = ev + base + (size_t)it * 4 * DM;
    float4 v0 = *(const float4*)p;
    float4 v1 = *(const float4*)(p + 4);
    uint4 o = { pack2(v0.x,v0.y), pack2(v0.z,v0.w), pack2(v1.x,v1.y), pack2(v1.z,v1.w) };
    *(uint4*)(evb + base + (size_t)it * 4 * DM) = o;
    s0+=v0.x; s1+=v0.y; s2+=v0.z; s3+=v0.w; s4+=v1.x; s5+=v1.y; s6+=v1.z; s7+=v1.w;
  }
  sred[w][lane*8+0]=s0; sred[w][lane*8+1]=s1; sred[w][lane*8+2]=s2; sred[w][lane*8+3]=s3;
  sred[w][lane*8+4]=s4; sred[w][lane*8+5]=s5; sred[w][lane*8+6]=s6; sred[w][lane*8+7]=s7;
  __syncthreads();
  const int di = t * 2;
  float t0 = sred[0][di] + sred[1][di] + sred[2][di] + sred[3][di];
  float t1 = sred[0][di+1] + sred[1][di+1] + sred[2][di+1] + sred[3][di+1];
  atomicAdd(&summary[b * DM + dsl * 512 + di],     t0 * (1.f / 1024.f));
  atomicAdd(&summary[b * DM + dsl * 512 + di + 1], t1 * (1.f / 1024.f));
}

// ---------------------------------------------------------------------------
// Kcvt_cur: cur_bf = bf16(current); fused gate logits gate_acc[b][l] += cur·gate_w
// Grid 1024 = b(4) x dsl(8) x rgrp(32, 64 rows). Block 256 = 4 waves; wave owns a row
// per iter -> in-wave shfl reduce for the gate partial (no LDS, no barrier).
// gate_w slice kept in registers (fixed per lane).
// ---------------------------------------------------------------------------
__launch_bounds__(256)
__global__ void k_cvt_cur(const float* __restrict__ cur, const float* __restrict__ gate_w,
                          unsigned short* __restrict__ curb, float* __restrict__ gate_acc) {
  const int bid = blockIdx.x;
  const int dsl = bid & 7, rgrp = (bid >> 3) & 31, b = bid >> 8;
  const int t = threadIdx.x;
  const int w = t >> 6, lane = t & 63;
  const int d = dsl * 512 + lane * 8;
  const int l0 = rgrp * 64 + w;
  float4 g0 = *(const float4*)(gate_w + d);
  float4 g1 = *(const float4*)(gate_w + d + 4);
  const size_t base = ((size_t)(b * SQ + l0)) * DM + d;
#pragma unroll 4
  for (int it = 0; it < 16; ++it) {
    const float* p = cur + base + (size_t)it * 4 * DM;
    float4 v0 = *(const float4*)p;
    float4 v1 = *(const float4*)(p + 4);
    uint4 o = { pack2(v0.x,v0.y), pack2(v0.z,v0.w), pack2(v1.x,v1.y), pack2(v1.z,v1.w) };
    *(uint4*)(curb + base + (size_t)it * 4 * DM) = o;
    float gp = v0.x*g0.x + v0.y*g0.y + v0.z*g0.z + v0.w*g0.w
             + v1.x*g1.x + v1.y*g1.y + v1.z*g1.z + v1.w*g1.w;
#pragma unroll
    for (int off = 32; off > 0; off >>= 1) gp += __shfl_xor(gp, off);
    if (lane == 0) atomicAdd(&gate_acc[b * SQ + l0 + it * 4], gp);
  }
}

// ---------------------------------------------------------------------------
// Kcvt_w: Wk, Wq -> bf16. Grid 256 (128 blocks each).
// ---------------------------------------------------------------------------
__launch_bounds__(256)
__global__ void k_cvt_w(const float* __restrict__ Wk, const float* __restrict__ Wq,
                        unsigned short* __restrict__ wkb, unsigned short* __restrict__ wqb) {
  const int bid = blockIdx.x;
  const float* src = (bid < 128) ? Wk : Wq;
  unsigned short* dst = (bid < 128) ? wkb : wqb;
  const int off = (bid & 127) * 2048 + threadIdx.x * 8;
  float4 v0 = *(const float4*)(src + off);
  float4 v1 = *(const float4*)(src + off + 4);
  uint4 o = { pack2(v0.x,v0.y), pack2(v0.z,v0.w), pack2(v1.x,v1.y), pack2(v1.z,v1.w) };
  *(uint4*)(dst + off) = o;
}

// ---------------------------------------------------------------------------
// K1: keys_part[ks][b][s][n] = partial over d-slice of evicted·W_key (bf16 inputs).
// Grid 512 = B(4) x MT(16) x KS(8). Block 256 = 4 waves; 64x64 tile, BK=64.
// Staging is now pure bf16 copy: 4 uint4 loads + 4 LDS stores per chunk.
// ---------------------------------------------------------------------------
__launch_bounds__(256)
__global__ void k_keys(const unsigned short* __restrict__ evb, const unsigned short* __restrict__ wkb,
                       float* __restrict__ keys_part) {
  __shared__ __align__(16) unsigned short As[2][64][72];
  __shared__ __align__(16) unsigned short Bs[2][64][72];
  const int bid = blockIdx.x;
  const int ks = bid & 7, mt = (bid >> 3) & 15, b = bid >> 7;
  const int n0 = mt * 64;
  const int t = threadIdx.x;
  const int w = t >> 6, m15 = t & 15, quad = (t & 63) >> 4;
  const int rowS = t >> 2, seg = (t & 3) * 16;

  f32x4 acc[4];
#pragma unroll
  for (int i = 0; i < 4; ++i) acc[i] = (f32x4){0.f, 0.f, 0.f, 0.f};

  const unsigned short* ap = evb + ((size_t)(b * NE + n0 + rowS)) * DM + ks * 512 + seg;
  const unsigned short* bp = wkb + (size_t)rowS * DM + ks * 512 + seg;

  uint4 a0 = *(const uint4*)ap, a1 = *(const uint4*)(ap + 8);
  uint4 b0 = *(const uint4*)bp, b1 = *(const uint4*)(bp + 8);
  int cur = 0;
  for (int ch = 0; ch < 8; ++ch) {
    *(uint4*)&As[cur][rowS][seg]     = a0;
    *(uint4*)&As[cur][rowS][seg + 8] = a1;
    *(uint4*)&Bs[cur][rowS][seg]     = b0;
    *(uint4*)&Bs[cur][rowS][seg + 8] = b1;
    __syncthreads();
    if (ch < 7) {
      ap += 64; bp += 64;
      a0 = *(const uint4*)ap; a1 = *(const uint4*)(ap + 8);
      b0 = *(const uint4*)bp; b1 = *(const uint4*)(bp + 8);
    }
#pragma unroll
    for (int kk = 0; kk < 2; ++kk) {
      bf16x8 af = *(const bf16x8*)&As[cur][w * 16 + m15][kk * 32 + quad * 8];
#pragma unroll
      for (int tn = 0; tn < 4; ++tn) {
        bf16x8 bfr = *(const bf16x8*)&Bs[cur][tn * 16 + m15][kk * 32 + quad * 8];
        acc[tn] = __builtin_amdgcn_mfma_f32_16x16x32_bf16(af, bfr, acc[tn], 0, 0, 0);
      }
    }
    cur ^= 1;
  }
  // D frag: row (= token n) = quad*4+r, col (= s) = m15. 4 consecutive n -> float4 store.
  const int n = n0 + w * 16 + quad * 4;
#pragma unroll
  for (int tn = 0; tn < 4; ++tn) {
    const int s = tn * 16 + m15;
    float4 v = { acc[tn][0], acc[tn][1], acc[tn][2], acc[tn][3] };
    *(float4*)&keys_part[(size_t)ks * (NB * DSZ * NE) + ((size_t)(b * DSZ + s)) * NE + n] = v;
  }
}

// ---------------------------------------------------------------------------
// Kbeta: beta[b][s] = sigmoid(summary[b]·W_beta_w[s] + W_beta_b[s]). Grid 256.
// ---------------------------------------------------------------------------
__launch_bounds__(256)
__global__ void k_beta(const float* __restrict__ summary, const float* __restrict__ Wbw,
                       const float* __restrict__ Wbb, float* __restrict__ beta) {
  __shared__ float wred[4];
  const int b = blockIdx.x >> 6, s = blockIdx.x & 63;
  const int t = threadIdx.x;
  const float* sp = summary + b * DM + t * 16;
  const float* wp = Wbw + (size_t)s * DM + t * 16;
  float acc = 0.f;
#pragma unroll
  for (int j = 0; j < 4; ++j) {
    float4 a  = *(const float4*)(sp + j * 4);
    float4 w4 = *(const float4*)(wp + j * 4);
    acc += a.x * w4.x + a.y * w4.y + a.z * w4.z + a.w * w4.w;
  }
#pragma unroll
  for (int off = 32; off > 0; off >>= 1) acc += __shfl_xor(acc, off);
  if ((t & 63) == 0) wred[t >> 6] = acc;
  __syncthreads();
  if (t == 0) {
    float x = wred[0] + wred[1] + wred[2] + wred[3] + Wbb[s];
    beta[b * DSZ + s] = 1.f / (1.f + expf(-x));
  }
}

// ---------------------------------------------------------------------------
// K2: softmax over n (sums the 8 K-split slabs), writes ww_t[b][s][n] in bf16.
// Grid 256 = one block per (b,s). Wave shfl reductions (2 barriers).
// ---------------------------------------------------------------------------
__launch_bounds__(256)
__global__ void k_softmax(const float* __restrict__ keys_part, unsigned short* __restrict__ ww_t) {
  __shared__ float wred[8];
  const int b = blockIdx.x >> 6, s = blockIdx.x & 63;
  const int t = threadIdx.x;
  const size_t base = ((size_t)(b * DSZ + s)) * NE + t * 4;
  float4 k = {0.f, 0.f, 0.f, 0.f};
#pragma unroll
  for (int sl = 0; sl < 8; ++sl) {
    float4 p = *(const float4*)&keys_part[(size_t)sl * (NB * DSZ * NE) + base];
    k.x += p.x; k.y += p.y; k.z += p.z; k.w += p.w;
  }
  float m = fmaxf(fmaxf(k.x, k.y), fmaxf(k.z, k.w));
#pragma unroll
  for (int off = 32; off > 0; off >>= 1) m = fmaxf(m, __shfl_xor(m, off));
  if ((t & 63) == 0) wred[t >> 6] = m;
  __syncthreads();
  const float M = fmaxf(fmaxf(wred[0], wred[1]), fmaxf(wred[2], wred[3]));
  float4 e = { expf(k.x - M), expf(k.y - M), expf(k.z - M), expf(k.w - M) };
  float ss = e.x + e.y + e.z + e.w;
#pragma unroll
  for (int off = 32; off > 0; off >>= 1) ss += __shfl_xor(ss, off);
  if ((t & 63) == 0) wred[4 + (t >> 6)] = ss;
  __syncthreads();
  const float inv = 1.f / (wred[4] + wred[5] + wred[6] + wred[7]);
  ushort4 o = { (unsigned short)f2bf(e.x * inv), (unsigned short)f2bf(e.y * inv),
                (unsigned short)f2bf(e.z * inv), (unsigned short)f2bf(e.w * inv) };
  *(ushort4*)&ww_t[((size_t)(b * DSZ + s)) * NE + t * 4] = o;
}

// ---------------------------------------------------------------------------
// K3: new_state^T[b][d][s] (bf16) = beta[b][s]*state[b][s][d] + sum_n ww[b][s][n]*ev[b][n][d]
// Grid 512 = B(4) x DT(128, 32-wide d tiles). Block 256 = 4 waves.
// M=64(s) x N=32(d), BK=64(n). ev read as bf16; transpose via bit ops (no pack).
// ---------------------------------------------------------------------------
__launch_bounds__(256)
__global__ void k_update(const unsigned short* __restrict__ evb, const float* __restrict__ state,
                         const float* __restrict__ beta, const unsigned short* __restrict__ ww_t,
                         unsigned short* __restrict__ ns_t) {
  __shared__ __align__(16) unsigned short Aw[2][64][72];  // [s][n]
  __shared__ __align__(16) unsigned short Bt[2][32][72];  // [d][n]
  const int bid = blockIdx.x;
  const int dt = bid & 127, b = bid >> 7;
  const int d0 = dt * 32;
  const int t = threadIdx.x;
  const int w = t >> 6, m15 = t & 15, quad = (t & 63) >> 4;
  const int rowS = t >> 2, seg = (t & 3) * 16;
  const int npair = (t & 31) * 2, dquad = (t >> 5) * 4;

  f32x4 acc[2];
#pragma unroll
  for (int i = 0; i < 2; ++i) acc[i] = (f32x4){0.f, 0.f, 0.f, 0.f};

  const unsigned short* wp = ww_t + ((size_t)(b * DSZ + rowS)) * NE + seg;
  const unsigned short* ep = evb + ((size_t)(b * NE + npair)) * DM + d0 + dquad;

  uint4 wa = *(const uint4*)(wp), wb = *(const uint4*)(wp + 8);
  uint2 r0 = *(const uint2*)(ep), r1 = *(const uint2*)(ep + DM);
  int cur = 0;
  for (int ch = 0; ch < 16; ++ch) {
    *(uint4*)&Aw[cur][rowS][seg]     = wa;
    *(uint4*)&Aw[cur][rowS][seg + 8] = wb;
    // Bt[d][n] pairs: low = ev[n][d], high = ev[n+1][d]
    *(unsigned*)&Bt[cur][dquad + 0][npair] = (r0.x & 0xffffu) | (r1.x << 16);
    *(unsigned*)&Bt[cur][dquad + 1][npair] = (r0.x >> 16) | (r1.x & 0xffff0000u);
    *(unsigned*)&Bt[cur][dquad + 2][npair] = (r0.y & 0xffffu) | (r1.y << 16);
    *(unsigned*)&Bt[cur][dquad + 3][npair] = (r0.y >> 16) | (r1.y & 0xffff0000u);
    __syncthreads();
    if (ch < 15) {
      wp += 64; ep += (size_t)64 * DM;
      wa = *(const uint4*)(wp); wb = *(const uint4*)(wp + 8);
      r0 = *(const uint2*)(ep); r1 = *(const uint2*)(ep + DM);
    }
#pragma unroll
    for (int kk = 0; kk < 2; ++kk) {
      bf16x8 af = *(const bf16x8*)&Aw[cur][w * 16 + m15][kk * 32 + quad * 8];
#pragma unroll
      for (int tn = 0; tn < 2; ++tn) {
        bf16x8 bfr = *(const bf16x8*)&Bt[cur][tn * 16 + m15][kk * 32 + quad * 8];
        acc[tn] = __builtin_amdgcn_mfma_f32_16x16x32_bf16(af, bfr, acc[tn], 0, 0, 0);
      }
    }
    cur ^= 1;
  }
  // D frag: row = s = w*16+quad*4+r, col = d = d0+tn*16+m15. Store transposed [d][s].
  const int sbase = w * 16 + quad * 4;
#pragma unroll
  for (int tn = 0; tn < 2; ++tn) {
    const int d = d0 + tn * 16 + m15;
    float v[4];
#pragma unroll
    for (int r = 0; r < 4; ++r) {
      const int s = sbase + r;
      v[r] = beta[b * DSZ + s] * state[((size_t)(b * DSZ + s)) * DM + d] + acc[tn][r];
    }
    ushort4 o = { (unsigned short)f2bf(v[0]), (unsigned short)f2bf(v[1]),
                  (unsigned short)f2bf(v[2]), (unsigned short)f2bf(v[3]) };
    *(ushort4*)&ns_t[((size_t)(b * DM + d)) * DSZ + sbase] = o;
  }
}

// ---------------------------------------------------------------------------
// K4: q_part[ks][b][l][s] = partial current·W_query (bf16 inputs). Gate moved to cvt_cur.
// Grid 512 = B x MT(32) x KS(4). Block 256 = 4 waves.
// ---------------------------------------------------------------------------
__launch_bounds__(256)
__global__ void k_q(const unsigned short* __restrict__ curb, const unsigned short* __restrict__ wqb,
                    float* __restrict__ q_part) {
  __shared__ __align__(16) unsigned short As[2][64][72];
  __shared__ __align__(16) unsigned short Bs[2][64][72];
  const int bid = blockIdx.x;
  const int ks = bid & 3, mt = (bid >> 2) & 31, b = bid >> 7;
  const int l0 = mt * 64;
  const int t = threadIdx.x;
  const int w = t >> 6, m15 = t & 15, quad = (t & 63) >> 4;
  const int rowS = t >> 2, seg = (t & 3) * 16;

  f32x4 acc[4];
#pragma unroll
  for (int i = 0; i < 4; ++i) acc[i] = (f32x4){0.f, 0.f, 0.f, 0.f};

  const unsigned short* ap = curb + ((size_t)(b * SQ + l0 + rowS)) * DM + ks * 1024 + seg;
  const unsigned short* bp = wqb + (size_t)rowS * DM + ks * 1024 + seg;

  uint4 a0 = *(const uint4*)ap, a1 = *(const uint4*)(ap + 8);
  uint4 b0 = *(const uint4*)bp, b1 = *(const uint4*)(bp + 8);
  int cur = 0;
  for (int ch = 0; ch < 16; ++ch) {
    *(uint4*)&As[cur][rowS][seg]     = a0;
    *(uint4*)&As[cur][rowS][seg + 8] = a1;
    *(uint4*)&Bs[cur][rowS][seg]     = b0;
    *(uint4*)&Bs[cur][rowS][seg + 8] = b1;
    __syncthreads();
    if (ch < 15) {
      ap += 64; bp += 64;
      a0 = *(const uint4*)ap; a1 = *(const uint4*)(ap + 8);
      b0 = *(const uint4*)bp; b1 = *(const uint4*)(bp + 8);
    }
#pragma unroll
    for (int kk = 0; kk < 2; ++kk) {
      bf16x8 af = *(const bf16x8*)&As[cur][w * 16 + m15][kk * 32 + quad * 8];
#pragma unroll
      for (int tn = 0; tn < 4; ++tn) {
        bf16x8 bfr = *(const bf16x8*)&Bs[cur][tn * 16 + m15][kk * 32 + quad * 8];
        acc[tn] = __builtin_amdgcn_mfma_f32_16x16x32_bf16(af, bfr, acc[tn], 0, 0, 0);
      }
    }
    cur ^= 1;
  }
  // q partial stores: row = l, col = s
  const int lrow = l0 + w * 16 + quad * 4;
#pragma unroll
  for (int tn = 0; tn < 4; ++tn) {
#pragma unroll
    for (int r = 0; r < 4; ++r) {
      q_part[(size_t)ks * (NB * SQ * DSZ) + ((size_t)(b * SQ + lrow + r)) * DSZ + tn * 16 + m15] =
          acc[tn][r];
    }
  }
}

// ---------------------------------------------------------------------------
// Kqcvt: qbf[b][l][s] = bf16( sum of 4 q_part slabs ). Grid 512.
// ---------------------------------------------------------------------------
__launch_bounds__(256)
__global__ void k_qcvt(const float* __restrict__ q_part, unsigned short* __restrict__ qbf) {
  const int i = (blockIdx.x * 256 + threadIdx.x) * 4;
  const int SL = NB * SQ * DSZ;
  float4 v0 = *(const float4*)&q_part[i];
  float4 v1 = *(const float4*)&q_part[i + SL];
  float4 v2 = *(const float4*)&q_part[i + 2 * SL];
  float4 v3 = *(const float4*)&q_part[i + 3 * SL];
  float x = v0.x + v1.x + v2.x + v3.x;
  float y = v0.y + v1.y + v2.y + v3.y;
  float z = v0.z + v1.z + v2.z + v3.z;
  float u = v0.w + v1.w + v2.w + v3.w;
  ushort4 o = { (unsigned short)f2bf(x), (unsigned short)f2bf(y),
                (unsigned short)f2bf(z), (unsigned short)f2bf(u) };
  *(ushort4*)&qbf[i] = o;
}

// ---------------------------------------------------------------------------
// K5: out[b][l][d] = sigmoid(gate_acc[b][l]+gate_b) * sum_s q[l][s]*ns_t[d][s]
// Grid 8192 = B(4) x LT(32) x DT(64); block 256 = 4 waves; no LDS, frags from global.
// ---------------------------------------------------------------------------
__launch_bounds__(256)
__global__ void k_out(const unsigned short* __restrict__ qbf, const unsigned short* __restrict__ ns_t,
                      const float* __restrict__ gate_acc, const float* __restrict__ gate_b,
                      float* __restrict__ out) {
  const int bid = blockIdx.x;
  const int dt = bid & 63, lt = (bid >> 6) & 31, b = bid >> 11;
  const int d0 = dt * 64, l0 = lt * 64;
  const int t = threadIdx.x;
  const int w = t >> 6, m15 = t & 15, quad = (t & 63) >> 4;
  const int la = l0 + w * 16 + m15;
  f32x4 acc[4];
#pragma unroll
  for (int i = 0; i < 4; ++i) acc[i] = (f32x4){0.f, 0.f, 0.f, 0.f};
#pragma unroll
  for (int kk = 0; kk < 2; ++kk) {
    bf16x8 af = *(const bf16x8*)&qbf[((size_t)(b * SQ + la)) * DSZ + kk * 32 + quad * 8];
#pragma unroll
    for (int tn = 0; tn < 4; ++tn) {
      const int d = d0 + tn * 16 + m15;
      bf16x8 bfr = *(const bf16x8*)&ns_t[((size_t)(b * DM + d)) * DSZ + kk * 32 + quad * 8];
      acc[tn] = __builtin_amdgcn_mfma_f32_16x16x32_bf16(af, bfr, acc[tn], 0, 0, 0);
    }
  }
  const float gb = gate_b[0];
  const int lbase = l0 + w * 16 + quad * 4;
  float g[4];
#pragma unroll
  for (int r = 0; r < 4; ++r)
    g[r] = 1.f / (1.f + expf(-(gate_acc[b * SQ + lbase + r] + gb)));
#pragma unroll
  for (int tn = 0; tn < 4; ++tn) {
    const int d = d0 + tn * 16 + m15;
#pragma unroll
    for (int r = 0; r < 4; ++r)
      out[((size_t)(b * SQ + lbase + r)) * DM + d] = g[r] * acc[tn][r];
  }
}

// ---------------------------------------------------------------------------
extern "C" void kernel_launch(void* const* d_in, const int* in_sizes, int n_in,
                              void* d_out, int out_size, void* d_ws, size_t ws_size,
                              hipStream_t stream) {
  const float* state   = (const float*)d_in[0];
  const float* evicted = (const float*)d_in[1];
  const float* current = (const float*)d_in[2];
  const float* Wkey    = (const float*)d_in[3];
  const float* Wbw     = (const float*)d_in[4];
  const float* Wbb     = (const float*)d_in[5];
  const float* Wq      = (const float*)d_in[6];
  const float* gate_w  = (const float*)d_in[7];
  const float* gate_b  = (const float*)d_in[8];
  float* out = (float*)d_out;

  // workspace layout (~117 MB total)
  float* f = (float*)d_ws;
  float* keys_part = f;                              // 8 * 262144 f  (8 MB)
  float* q_part    = keys_part + 8 * 262144;         // 4 * 524288 f  (8 MB)
  float* summary   = q_part + 4 * 524288;            // 16384 f
  float* gate_acc  = summary + 16384;                // 8192 f
  float* beta      = gate_acc + 8192;                // 256 f
  unsigned short* ww_t = (unsigned short*)(beta + 256);  // 262144 us (512 KB)
  unsigned short* qbf  = ww_t + 262144;                  // 524288 us (1 MB)
  unsigned short* ns_t = qbf + 524288;                   // 1048576 us (2 MB)
  unsigned short* evb  = ns_t + 1048576;                 // 16777216 us (32 MB)
  unsigned short* curb = evb + 16777216;                 // 33554432 us (64 MB)
  unsigned short* wkb  = curb + 33554432;                // 262144 us (512 KB)
  unsigned short* wqb  = wkb + 262144;                   // 262144 us (512 KB)

  // zero only the atomically-accumulated buffers (summary + gate_acc, contiguous)
  hipMemsetAsync(summary, 0, (16384 + 8192) * sizeof(float), stream);

  k_cvt_w  <<<256,  256, 0, stream>>>(Wkey, Wq, wkb, wqb);
  k_cvt_ev <<<512,  256, 0, stream>>>(evicted, evb, summary);
  k_cvt_cur<<<1024, 256, 0, stream>>>(current, gate_w, curb, gate_acc);
  k_keys   <<<512,  256, 0, stream>>>(evb, wkb, keys_part);
  k_beta   <<<256,  256, 0, stream>>>(summary, Wbw, Wbb, beta);
  k_softmax<<<256,  256, 0, stream>>>(keys_part, ww_t);
  k_update <<<512,  256, 0, stream>>>(evb, state, beta, ww_t, ns_t);
  k_q      <<<512,  256, 0, stream>>>(curb, wqb, q_part);
  k_qcvt   <<<512,  256, 0, stream>>>(q_part, qbf);
  k_out    <<<8192, 256, 0, stream>>>(qbf, ns_t, gate_acc, gate_b, out);
}

// Round 3
// 391.732 us; speedup vs baseline: 1.0286x; 1.0286x over previous
//
#include <hip/hip_runtime.h>

// Problem constants
#define DM 4096   // d_model
#define DSZ 64    // d_state
#define NE 1024   // num evicted
#define SQ 2048   // seq len
#define NB 4      // batch

typedef __attribute__((ext_vector_type(8))) short bf16x8;
typedef __attribute__((ext_vector_type(4))) float f32x4;

__device__ __forceinline__ unsigned f2bf(float f) {
  union { float f; unsigned u; } v; v.f = f;
  return (v.u + 0x7fffu + ((v.u >> 16) & 1u)) >> 16;  // RNE fp32->bf16
}
__device__ __forceinline__ unsigned pack2(float lo, float hi) {
  return f2bf(lo) | (f2bf(hi) << 16);
}
__device__ __forceinline__ float bf2f(unsigned short h) {
  union { unsigned u; float f; } v; v.u = ((unsigned)h) << 16; return v.f;
}

__device__ __forceinline__ void load8(const float* __restrict__ ap, const float* __restrict__ bp,
                                      float4& a0, float4& a1, float4& a2, float4& a3,
                                      float4& b0, float4& b1, float4& b2, float4& b3) {
  a0 = *(const float4*)(ap);      a1 = *(const float4*)(ap + 4);
  a2 = *(const float4*)(ap + 8);  a3 = *(const float4*)(ap + 12);
  b0 = *(const float4*)(bp);      b1 = *(const float4*)(bp + 4);
  b2 = *(const float4*)(bp + 8);  b3 = *(const float4*)(bp + 12);
}

// ---------------------------------------------------------------------------
// K1 (fused): keys_part[ks][b][s][n] partials of evicted·W_key; ALSO writes
// evb = bf16(evicted) (reused by k_update) and summary column-sum partials.
// Grid 512 = B(4) x MT(16) x KS(8). Block 256 = 4 waves; 64x64 tile, BK=64.
// ev is read fp32 ONCE here; this kernel replaces k_sum/k_cvt_ev entirely.
// ---------------------------------------------------------------------------
__launch_bounds__(256)
__global__ void k_keys(const float* __restrict__ ev, const float* __restrict__ Wk,
                       float* __restrict__ keys_part, unsigned short* __restrict__ evb,
                       float* __restrict__ summary) {
  __shared__ __align__(16) unsigned short As[2][64][72];
  __shared__ __align__(16) unsigned short Bs[2][64][72];
  __shared__ float csum[8][4][64];  // per-chunk column partial sums (8 KB)
  const int bid = blockIdx.x;
  const int ks = bid & 7, mt = (bid >> 3) & 15, b = bid >> 7;
  const int n0 = mt * 64;
  const int t = threadIdx.x;
  const int w = t >> 6, m15 = t & 15, quad = (t & 63) >> 4;
  const int rowS = t >> 2, seg = (t & 3) * 16;
  const int ccol = t & 63, cgrp = t >> 6;

  f32x4 acc[4];
#pragma unroll
  for (int i = 0; i < 4; ++i) acc[i] = (f32x4){0.f, 0.f, 0.f, 0.f};

  const float* ap = ev + ((size_t)(b * NE + n0 + rowS)) * DM + ks * 512 + seg;
  const float* bp = Wk + (size_t)rowS * DM + ks * 512 + seg;
  unsigned short* evp = evb + ((size_t)(b * NE + n0 + rowS)) * DM + ks * 512 + seg;

  float4 a0, a1, a2, a3, b0, b1, b2, b3;
  load8(ap, bp, a0, a1, a2, a3, b0, b1, b2, b3);
  int cur = 0;
  for (int ch = 0; ch < 8; ++ch) {
    uint4 pa0 = { pack2(a0.x,a0.y), pack2(a0.z,a0.w), pack2(a1.x,a1.y), pack2(a1.z,a1.w) };
    uint4 pa1 = { pack2(a2.x,a2.y), pack2(a2.z,a2.w), pack2(a3.x,a3.y), pack2(a3.z,a3.w) };
    *(uint4*)&As[cur][rowS][seg]     = pa0;
    *(uint4*)&As[cur][rowS][seg + 8] = pa1;
    *(uint4*)&Bs[cur][rowS][seg]     = (uint4){ pack2(b0.x,b0.y), pack2(b0.z,b0.w), pack2(b1.x,b1.y), pack2(b1.z,b1.w) };
    *(uint4*)&Bs[cur][rowS][seg + 8] = (uint4){ pack2(b2.x,b2.y), pack2(b2.z,b2.w), pack2(b3.x,b3.y), pack2(b3.z,b3.w) };
    *(uint4*)(evp)     = pa0;   // evb write: same data, coalesced 32B/thread
    *(uint4*)(evp + 8) = pa1;
    __syncthreads();
    if (ch < 7) {  // prefetch next chunk; latency hides under MFMA below
      ap += 64; bp += 64; evp += 64;
      load8(ap, bp, a0, a1, a2, a3, b0, b1, b2, b3);
    }
    {  // column sums of this chunk's A-tile (for summary)
      float cs = 0.f;
#pragma unroll
      for (int r = 0; r < 16; ++r) cs += bf2f(As[cur][cgrp * 16 + r][ccol]);
      csum[ch][cgrp][ccol] = cs;
    }
#pragma unroll
    for (int kk = 0; kk < 2; ++kk) {
      bf16x8 af = *(const bf16x8*)&As[cur][w * 16 + m15][kk * 32 + quad * 8];
#pragma unroll
      for (int tn = 0; tn < 4; ++tn) {
        bf16x8 bfr = *(const bf16x8*)&Bs[cur][tn * 16 + m15][kk * 32 + quad * 8];
        acc[tn] = __builtin_amdgcn_mfma_f32_16x16x32_bf16(af, bfr, acc[tn], 0, 0, 0);
      }
    }
    cur ^= 1;
  }
  // D frag: row (= token n) = quad*4+r, col (= s) = m15. 4 consecutive n -> float4 store.
  const int n = n0 + w * 16 + quad * 4;
#pragma unroll
  for (int tn = 0; tn < 4; ++tn) {
    const int s = tn * 16 + m15;
    float4 v = { acc[tn][0], acc[tn][1], acc[tn][2], acc[tn][3] };
    *(float4*)&keys_part[(size_t)ks * (NB * DSZ * NE) + ((size_t)(b * DSZ + s)) * NE + n] = v;
  }
  // summary flush: 64 threads, 8 chunks' columns each; 16 mt-blocks contend per addr
  __syncthreads();
  if (t < 64) {
#pragma unroll
    for (int c2 = 0; c2 < 8; ++c2) {
      float ssum = csum[c2][0][t] + csum[c2][1][t] + csum[c2][2][t] + csum[c2][3][t];
      atomicAdd(&summary[b * DM + ks * 512 + c2 * 64 + t], ssum * (1.f / 1024.f));
    }
  }
}

// ---------------------------------------------------------------------------
// K2 (merged): beta[b][s] = sigmoid(summary·Wbw[s] + Wbb[s]); softmax over n of
// the summed keys slabs -> ww_t[b][s][n] bf16. Grid 256 = one block per (b,s).
// ---------------------------------------------------------------------------
__launch_bounds__(256)
__global__ void k_bs(const float* __restrict__ summary, const float* __restrict__ Wbw,
                     const float* __restrict__ Wbb, const float* __restrict__ keys_part,
                     float* __restrict__ beta, unsigned short* __restrict__ ww_t) {
  __shared__ float wredb[4];
  __shared__ float wred[8];
  const int b = blockIdx.x >> 6, s = blockIdx.x & 63;
  const int t = threadIdx.x;
  // ---- beta dot ----
  {
    const float* sp = summary + b * DM + t * 16;
    const float* wp = Wbw + (size_t)s * DM + t * 16;
    float acc = 0.f;
#pragma unroll
    for (int j = 0; j < 4; ++j) {
      float4 a  = *(const float4*)(sp + j * 4);
      float4 w4 = *(const float4*)(wp + j * 4);
      acc += a.x * w4.x + a.y * w4.y + a.z * w4.z + a.w * w4.w;
    }
#pragma unroll
    for (int off = 32; off > 0; off >>= 1) acc += __shfl_xor(acc, off);
    if ((t & 63) == 0) wredb[t >> 6] = acc;
  }
  // ---- softmax ----
  const size_t base = ((size_t)(b * DSZ + s)) * NE + t * 4;
  float4 k = {0.f, 0.f, 0.f, 0.f};
#pragma unroll
  for (int sl = 0; sl < 8; ++sl) {
    float4 p = *(const float4*)&keys_part[(size_t)sl * (NB * DSZ * NE) + base];
    k.x += p.x; k.y += p.y; k.z += p.z; k.w += p.w;
  }
  float m = fmaxf(fmaxf(k.x, k.y), fmaxf(k.z, k.w));
#pragma unroll
  for (int off = 32; off > 0; off >>= 1) m = fmaxf(m, __shfl_xor(m, off));
  if ((t & 63) == 0) wred[t >> 6] = m;
  __syncthreads();
  const float M = fmaxf(fmaxf(wred[0], wred[1]), fmaxf(wred[2], wred[3]));
  float4 e = { expf(k.x - M), expf(k.y - M), expf(k.z - M), expf(k.w - M) };
  float ss = e.x + e.y + e.z + e.w;
#pragma unroll
  for (int off = 32; off > 0; off >>= 1) ss += __shfl_xor(ss, off);
  if ((t & 63) == 0) wred[4 + (t >> 6)] = ss;
  __syncthreads();
  const float inv = 1.f / (wred[4] + wred[5] + wred[6] + wred[7]);
  ushort4 o = { (unsigned short)f2bf(e.x * inv), (unsigned short)f2bf(e.y * inv),
                (unsigned short)f2bf(e.z * inv), (unsigned short)f2bf(e.w * inv) };
  *(ushort4*)&ww_t[((size_t)(b * DSZ + s)) * NE + t * 4] = o;
  if (t == 0) {
    float x = wredb[0] + wredb[1] + wredb[2] + wredb[3] + Wbb[s];
    beta[b * DSZ + s] = 1.f / (1.f + expf(-x));
  }
}

// ---------------------------------------------------------------------------
// K3: new_state^T[b][d][s] (bf16) = beta[b][s]*state[b][s][d] + sum_n ww[b][s][n]*ev[b][n][d]
// Grid 512 = B(4) x DT(128, 32-wide d tiles). Block 256 = 4 waves.
// M=64(s) x N=32(d), BK=64(n). ev read as bf16 (evb); transpose via bit ops.
// ---------------------------------------------------------------------------
__launch_bounds__(256)
__global__ void k_update(const unsigned short* __restrict__ evb, const float* __restrict__ state,
                         const float* __restrict__ beta, const unsigned short* __restrict__ ww_t,
                         unsigned short* __restrict__ ns_t) {
  __shared__ __align__(16) unsigned short Aw[2][64][72];  // [s][n]
  __shared__ __align__(16) unsigned short Bt[2][32][72];  // [d][n]
  const int bid = blockIdx.x;
  const int dt = bid & 127, b = bid >> 7;
  const int d0 = dt * 32;
  const int t = threadIdx.x;
  const int w = t >> 6, m15 = t & 15, quad = (t & 63) >> 4;
  const int rowS = t >> 2, seg = (t & 3) * 16;
  const int npair = (t & 31) * 2, dquad = (t >> 5) * 4;

  f32x4 acc[2];
#pragma unroll
  for (int i = 0; i < 2; ++i) acc[i] = (f32x4){0.f, 0.f, 0.f, 0.f};

  const unsigned short* wp = ww_t + ((size_t)(b * DSZ + rowS)) * NE + seg;
  const unsigned short* ep = evb + ((size_t)(b * NE + npair)) * DM + d0 + dquad;

  uint4 wa = *(const uint4*)(wp), wb = *(const uint4*)(wp + 8);
  uint2 r0 = *(const uint2*)(ep), r1 = *(const uint2*)(ep + DM);
  int cur = 0;
  for (int ch = 0; ch < 16; ++ch) {
    *(uint4*)&Aw[cur][rowS][seg]     = wa;
    *(uint4*)&Aw[cur][rowS][seg + 8] = wb;
    // Bt[d][n] pairs: low = ev[n][d], high = ev[n+1][d]
    *(unsigned*)&Bt[cur][dquad + 0][npair] = (r0.x & 0xffffu) | (r1.x << 16);
    *(unsigned*)&Bt[cur][dquad + 1][npair] = (r0.x >> 16) | (r1.x & 0xffff0000u);
    *(unsigned*)&Bt[cur][dquad + 2][npair] = (r0.y & 0xffffu) | (r1.y << 16);
    *(unsigned*)&Bt[cur][dquad + 3][npair] = (r0.y >> 16) | (r1.y & 0xffff0000u);
    __syncthreads();
    if (ch < 15) {
      wp += 64; ep += (size_t)64 * DM;
      wa = *(const uint4*)(wp); wb = *(const uint4*)(wp + 8);
      r0 = *(const uint2*)(ep); r1 = *(const uint2*)(ep + DM);
    }
#pragma unroll
    for (int kk = 0; kk < 2; ++kk) {
      bf16x8 af = *(const bf16x8*)&Aw[cur][w * 16 + m15][kk * 32 + quad * 8];
#pragma unroll
      for (int tn = 0; tn < 2; ++tn) {
        bf16x8 bfr = *(const bf16x8*)&Bt[cur][tn * 16 + m15][kk * 32 + quad * 8];
        acc[tn] = __builtin_amdgcn_mfma_f32_16x16x32_bf16(af, bfr, acc[tn], 0, 0, 0);
      }
    }
    cur ^= 1;
  }
  // D frag: row = s = w*16+quad*4+r, col = d = d0+tn*16+m15. Store transposed [d][s].
  const int sbase = w * 16 + quad * 4;
#pragma unroll
  for (int tn = 0; tn < 2; ++tn) {
    const int d = d0 + tn * 16 + m15;
    float v[4];
#pragma unroll
    for (int r = 0; r < 4; ++r) {
      const int s = sbase + r;
      v[r] = beta[b * DSZ + s] * state[((size_t)(b * DSZ + s)) * DM + d] + acc[tn][r];
    }
    ushort4 o = { (unsigned short)f2bf(v[0]), (unsigned short)f2bf(v[1]),
                  (unsigned short)f2bf(v[2]), (unsigned short)f2bf(v[3]) };
    *(ushort4*)&ns_t[((size_t)(b * DM + d)) * DSZ + sbase] = o;
  }
}

// ---------------------------------------------------------------------------
// K4: q_part[ks][b][l][s] = partial current·W_query; fused gate logit partials
// into gate_acc (atomic). Grid 512 = B x MT(32) x KS(4). cur read fp32 ONCE
// (bf16 round-trip is a net traffic loss for single-consumer data — R2 lesson).
// ---------------------------------------------------------------------------
__launch_bounds__(256)
__global__ void k_q(const float* __restrict__ cur_, const float* __restrict__ Wq,
                    const float* __restrict__ gate_w,
                    float* __restrict__ q_part, float* __restrict__ gate_acc) {
  __shared__ __align__(16) unsigned short As[2][64][72];
  __shared__ __align__(16) unsigned short Bs[2][64][72];
  __shared__ float gwAll[1024];
  __shared__ float gred[256];
  const int bid = blockIdx.x;
  const int ks = bid & 3, mt = (bid >> 2) & 31, b = bid >> 7;
  const int l0 = mt * 64;
  const int t = threadIdx.x;
  const int w = t >> 6, m15 = t & 15, quad = (t & 63) >> 4;
  const int rowS = t >> 2, seg = (t & 3) * 16;

  f32x4 acc[4];
#pragma unroll
  for (int i = 0; i < 4; ++i) acc[i] = (f32x4){0.f, 0.f, 0.f, 0.f};
  float gpart = 0.f;

  // hoist the whole gate_w K-slab once (4 KB)
  *(float4*)&gwAll[t * 4] = *(const float4*)(gate_w + ks * 1024 + t * 4);

  const float* ap = cur_ + ((size_t)(b * SQ + l0 + rowS)) * DM + ks * 1024 + seg;
  const float* bp = Wq + (size_t)rowS * DM + ks * 1024 + seg;

  float4 a0, a1, a2, a3, b0, b1, b2, b3;
  load8(ap, bp, a0, a1, a2, a3, b0, b1, b2, b3);
  int cur = 0;
  for (int ch = 0; ch < 16; ++ch) {
    *(uint4*)&As[cur][rowS][seg]     = (uint4){ pack2(a0.x,a0.y), pack2(a0.z,a0.w), pack2(a1.x,a1.y), pack2(a1.z,a1.w) };
    *(uint4*)&As[cur][rowS][seg + 8] = (uint4){ pack2(a2.x,a2.y), pack2(a2.z,a2.w), pack2(a3.x,a3.y), pack2(a3.z,a3.w) };
    *(uint4*)&Bs[cur][rowS][seg]     = (uint4){ pack2(b0.x,b0.y), pack2(b0.z,b0.w), pack2(b1.x,b1.y), pack2(b1.z,b1.w) };
    *(uint4*)&Bs[cur][rowS][seg + 8] = (uint4){ pack2(b2.x,b2.y), pack2(b2.z,b2.w), pack2(b3.x,b3.y), pack2(b3.z,b3.w) };
    __syncthreads();
    {  // gate dot on the still-live a-regs (gwAll valid after first barrier)
      const float* g = &gwAll[ch * 64 + seg];
      gpart += a0.x*g[0]  + a0.y*g[1]  + a0.z*g[2]  + a0.w*g[3]
             + a1.x*g[4]  + a1.y*g[5]  + a1.z*g[6]  + a1.w*g[7]
             + a2.x*g[8]  + a2.y*g[9]  + a2.z*g[10] + a2.w*g[11]
             + a3.x*g[12] + a3.y*g[13] + a3.z*g[14] + a3.w*g[15];
    }
    if (ch < 15) {
      ap += 64; bp += 64;
      load8(ap, bp, a0, a1, a2, a3, b0, b1, b2, b3);
    }
#pragma unroll
    for (int kk = 0; kk < 2; ++kk) {
      bf16x8 af = *(const bf16x8*)&As[cur][w * 16 + m15][kk * 32 + quad * 8];
#pragma unroll
      for (int tn = 0; tn < 4; ++tn) {
        bf16x8 bfr = *(const bf16x8*)&Bs[cur][tn * 16 + m15][kk * 32 + quad * 8];
        acc[tn] = __builtin_amdgcn_mfma_f32_16x16x32_bf16(af, bfr, acc[tn], 0, 0, 0);
      }
    }
    cur ^= 1;
  }
  // q partial stores: row = l, col = s
  const int lrow = l0 + w * 16 + quad * 4;
#pragma unroll
  for (int tn = 0; tn < 4; ++tn) {
#pragma unroll
    for (int r = 0; r < 4; ++r) {
      q_part[(size_t)ks * (NB * SQ * DSZ) + ((size_t)(b * SQ + lrow + r)) * DSZ + tn * 16 + m15] =
          acc[tn][r];
    }
  }
  // gate partial reduce: row index = t>>2, partials at t = 4r..4r+3
  gred[t] = gpart;
  __syncthreads();
  if (t < 64) {
    float tot = gred[4 * t] + gred[4 * t + 1] + gred[4 * t + 2] + gred[4 * t + 3];
    atomicAdd(&gate_acc[b * SQ + l0 + t], tot);
  }
}

// ---------------------------------------------------------------------------
// K5 (folded qcvt): out[b][l][d] = sigmoid(gate_acc+gate_b) * sum_s q[l][s]*ns_t[d][s]
// Sums the 4 q_part slabs in fp32, packs the 64x64 q-tile to LDS (L2 serves the
// re-reads across the 64 dt-blocks), then MFMA. Grid 8192 = B x LT(32) x DT(64).
// ---------------------------------------------------------------------------
__launch_bounds__(256)
__global__ void k_out(const float* __restrict__ q_part, const unsigned short* __restrict__ ns_t,
                      const float* __restrict__ gate_acc, const float* __restrict__ gate_b,
                      float* __restrict__ out) {
  __shared__ __align__(16) unsigned short Qs[64][72];
  const int bid = blockIdx.x;
  const int dt = bid & 63, lt = (bid >> 6) & 31, b = bid >> 11;
  const int d0 = dt * 64, l0 = lt * 64;
  const int t = threadIdx.x;
  const int w = t >> 6, m15 = t & 15, quad = (t & 63) >> 4;
  const int rowS = t >> 2, seg = (t & 3) * 16;
  {
    const int SL = NB * SQ * DSZ;
    const float* qp = q_part + ((size_t)(b * SQ + l0 + rowS)) * DSZ + seg;
    float4 s0 = {0,0,0,0}, s1 = s0, s2 = s0, s3 = s0;
#pragma unroll
    for (int sl = 0; sl < 4; ++sl) {
      const float* p = qp + (size_t)sl * SL;
      float4 u0 = *(const float4*)(p);
      float4 u1 = *(const float4*)(p + 4);
      float4 u2 = *(const float4*)(p + 8);
      float4 u3 = *(const float4*)(p + 12);
      s0.x += u0.x; s0.y += u0.y; s0.z += u0.z; s0.w += u0.w;
      s1.x += u1.x; s1.y += u1.y; s1.z += u1.z; s1.w += u1.w;
      s2.x += u2.x; s2.y += u2.y; s2.z += u2.z; s2.w += u2.w;
      s3.x += u3.x; s3.y += u3.y; s3.z += u3.z; s3.w += u3.w;
    }
    *(uint4*)&Qs[rowS][seg]     = (uint4){ pack2(s0.x,s0.y), pack2(s0.z,s0.w), pack2(s1.x,s1.y), pack2(s1.z,s1.w) };
    *(uint4*)&Qs[rowS][seg + 8] = (uint4){ pack2(s2.x,s2.y), pack2(s2.z,s2.w), pack2(s3.x,s3.y), pack2(s3.z,s3.w) };
  }
  __syncthreads();
  f32x4 acc[4];
#pragma unroll
  for (int i = 0; i < 4; ++i) acc[i] = (f32x4){0.f, 0.f, 0.f, 0.f};
#pragma unroll
  for (int kk = 0; kk < 2; ++kk) {
    bf16x8 af = *(const bf16x8*)&Qs[w * 16 + m15][kk * 32 + quad * 8];
#pragma unroll
    for (int tn = 0; tn < 4; ++tn) {
      const int d = d0 + tn * 16 + m15;
      bf16x8 bfr = *(const bf16x8*)&ns_t[((size_t)(b * DM + d)) * DSZ + kk * 32 + quad * 8];
      acc[tn] = __builtin_amdgcn_mfma_f32_16x16x32_bf16(af, bfr, acc[tn], 0, 0, 0);
    }
  }
  const float gb = gate_b[0];
  const int lbase = l0 + w * 16 + quad * 4;
  float g[4];
#pragma unroll
  for (int r = 0; r < 4; ++r)
    g[r] = 1.f / (1.f + expf(-(gate_acc[b * SQ + lbase + r] + gb)));
#pragma unroll
  for (int tn = 0; tn < 4; ++tn) {
    const int d = d0 + tn * 16 + m15;
#pragma unroll
    for (int r = 0; r < 4; ++r)
      out[((size_t)(b * SQ + lbase + r)) * DM + d] = g[r] * acc[tn][r];
  }
}

// ---------------------------------------------------------------------------
extern "C" void kernel_launch(void* const* d_in, const int* in_sizes, int n_in,
                              void* d_out, int out_size, void* d_ws, size_t ws_size,
                              hipStream_t stream) {
  const float* state   = (const float*)d_in[0];
  const float* evicted = (const float*)d_in[1];
  const float* current = (const float*)d_in[2];
  const float* Wkey    = (const float*)d_in[3];
  const float* Wbw     = (const float*)d_in[4];
  const float* Wbb     = (const float*)d_in[5];
  const float* Wq      = (const float*)d_in[6];
  const float* gate_w  = (const float*)d_in[7];
  const float* gate_b  = (const float*)d_in[8];
  float* out = (float*)d_out;

  // workspace layout (~51 MB total)
  float* f = (float*)d_ws;
  float* keys_part = f;                              // 8 * 262144 f  (8 MB)
  float* q_part    = keys_part + 8 * 262144;         // 4 * 524288 f  (8 MB)
  float* summary   = q_part + 4 * 524288;            // 16384 f
  float* gate_acc  = summary + 16384;                // 8192 f
  float* beta      = gate_acc + 8192;                // 256 f
  unsigned short* ww_t = (unsigned short*)(beta + 256);  // 262144 us (512 KB)
  unsigned short* ns_t = ww_t + 262144;                  // 1048576 us (2 MB)
  unsigned short* evb  = ns_t + 1048576;                 // 16777216 us (32 MB)

  // zero only the atomically-accumulated buffers (summary + gate_acc, contiguous)
  hipMemsetAsync(summary, 0, (16384 + 8192) * sizeof(float), stream);

  k_keys   <<<512,  256, 0, stream>>>(evicted, Wkey, keys_part, evb, summary);
  k_q      <<<512,  256, 0, stream>>>(current, Wq, gate_w, q_part, gate_acc);
  k_bs     <<<256,  256, 0, stream>>>(summary, Wbw, Wbb, keys_part, beta, ww_t);
  k_update <<<512,  256, 0, stream>>>(evb, state, beta, ww_t, ns_t);
  k_out    <<<8192, 256, 0, stream>>>(q_part, ns_t, gate_acc, gate_b, out);
}

// Round 4
// 354.115 us; speedup vs baseline: 1.1379x; 1.1062x over previous
//
#include <hip/hip_runtime.h>

// Problem constants
#define DM 4096   // d_model
#define DSZ 64    // d_state
#define NE 1024   // num evicted
#define SQ 2048   // seq len
#define NB 4      // batch

typedef __attribute__((ext_vector_type(8))) short bf16x8;
typedef __attribute__((ext_vector_type(4))) float f32x4;

__device__ __forceinline__ unsigned f2bf(float f) {
  union { float f; unsigned u; } v; v.f = f;
  return (v.u + 0x7fffu + ((v.u >> 16) & 1u)) >> 16;  // RNE fp32->bf16
}
__device__ __forceinline__ unsigned pack2(float lo, float hi) {
  return f2bf(lo) | (f2bf(hi) << 16);
}
__device__ __forceinline__ float bf2f(unsigned short h) {
  union { unsigned u; float f; } v; v.u = ((unsigned)h) << 16; return v.f;
}

__device__ __forceinline__ void load8(const float* __restrict__ ap, const float* __restrict__ bp,
                                      float4& a0, float4& a1, float4& a2, float4& a3,
                                      float4& b0, float4& b1, float4& b2, float4& b3) {
  a0 = *(const float4*)(ap);      a1 = *(const float4*)(ap + 4);
  a2 = *(const float4*)(ap + 8);  a3 = *(const float4*)(ap + 12);
  b0 = *(const float4*)(bp);      b1 = *(const float4*)(bp + 4);
  b2 = *(const float4*)(bp + 8);  b3 = *(const float4*)(bp + 12);
}

// ---------------------------------------------------------------------------
// K1 (fused): keys_part[ks][b][s][n] partials of evicted·W_key; ALSO writes
// evb = bf16(evicted) (reused by k_update) and summary column-sum partials.
// Grid 512 = B(4) x MT(16) x KS(8). Block 256 = 4 waves; 64x64 tile, BK=64.
// ---------------------------------------------------------------------------
__launch_bounds__(256)
__global__ void k_keys(const float* __restrict__ ev, const float* __restrict__ Wk,
                       float* __restrict__ keys_part, unsigned short* __restrict__ evb,
                       float* __restrict__ summary) {
  __shared__ __align__(16) unsigned short As[2][64][72];
  __shared__ __align__(16) unsigned short Bs[2][64][72];
  __shared__ float csum[8][4][64];  // per-chunk column partial sums (8 KB)
  const int bid = blockIdx.x;
  const int ks = bid & 7, mt = (bid >> 3) & 15, b = bid >> 7;
  const int n0 = mt * 64;
  const int t = threadIdx.x;
  const int w = t >> 6, m15 = t & 15, quad = (t & 63) >> 4;
  const int rowS = t >> 2, seg = (t & 3) * 16;
  const int ccol = t & 63, cgrp = t >> 6;

  f32x4 acc[4];
#pragma unroll
  for (int i = 0; i < 4; ++i) acc[i] = (f32x4){0.f, 0.f, 0.f, 0.f};

  const float* ap = ev + ((size_t)(b * NE + n0 + rowS)) * DM + ks * 512 + seg;
  const float* bp = Wk + (size_t)rowS * DM + ks * 512 + seg;
  unsigned short* evp = evb + ((size_t)(b * NE + n0 + rowS)) * DM + ks * 512 + seg;

  float4 a0, a1, a2, a3, b0, b1, b2, b3;
  load8(ap, bp, a0, a1, a2, a3, b0, b1, b2, b3);
  int cur = 0;
  for (int ch = 0; ch < 8; ++ch) {
    uint4 pa0 = { pack2(a0.x,a0.y), pack2(a0.z,a0.w), pack2(a1.x,a1.y), pack2(a1.z,a1.w) };
    uint4 pa1 = { pack2(a2.x,a2.y), pack2(a2.z,a2.w), pack2(a3.x,a3.y), pack2(a3.z,a3.w) };
    *(uint4*)&As[cur][rowS][seg]     = pa0;
    *(uint4*)&As[cur][rowS][seg + 8] = pa1;
    *(uint4*)&Bs[cur][rowS][seg]     = (uint4){ pack2(b0.x,b0.y), pack2(b0.z,b0.w), pack2(b1.x,b1.y), pack2(b1.z,b1.w) };
    *(uint4*)&Bs[cur][rowS][seg + 8] = (uint4){ pack2(b2.x,b2.y), pack2(b2.z,b2.w), pack2(b3.x,b3.y), pack2(b3.z,b3.w) };
    *(uint4*)(evp)     = pa0;   // evb write: same data, coalesced 32B/thread
    *(uint4*)(evp + 8) = pa1;
    __syncthreads();
    if (ch < 7) {  // prefetch next chunk; latency hides under MFMA below
      ap += 64; bp += 64; evp += 64;
      load8(ap, bp, a0, a1, a2, a3, b0, b1, b2, b3);
    }
    {  // column sums of this chunk's A-tile (for summary)
      float cs = 0.f;
#pragma unroll
      for (int r = 0; r < 16; ++r) cs += bf2f(As[cur][cgrp * 16 + r][ccol]);
      csum[ch][cgrp][ccol] = cs;
    }
#pragma unroll
    for (int kk = 0; kk < 2; ++kk) {
      bf16x8 af = *(const bf16x8*)&As[cur][w * 16 + m15][kk * 32 + quad * 8];
#pragma unroll
      for (int tn = 0; tn < 4; ++tn) {
        bf16x8 bfr = *(const bf16x8*)&Bs[cur][tn * 16 + m15][kk * 32 + quad * 8];
        acc[tn] = __builtin_amdgcn_mfma_f32_16x16x32_bf16(af, bfr, acc[tn], 0, 0, 0);
      }
    }
    cur ^= 1;
  }
  // D frag: row (= token n) = quad*4+r, col (= s) = m15. 4 consecutive n -> float4 store.
  const int n = n0 + w * 16 + quad * 4;
#pragma unroll
  for (int tn = 0; tn < 4; ++tn) {
    const int s = tn * 16 + m15;
    float4 v = { acc[tn][0], acc[tn][1], acc[tn][2], acc[tn][3] };
    *(float4*)&keys_part[(size_t)ks * (NB * DSZ * NE) + ((size_t)(b * DSZ + s)) * NE + n] = v;
  }
  // summary flush: 64 threads, 8 chunks' columns each
  __syncthreads();
  if (t < 64) {
#pragma unroll
    for (int c2 = 0; c2 < 8; ++c2) {
      float ssum = csum[c2][0][t] + csum[c2][1][t] + csum[c2][2][t] + csum[c2][3][t];
      atomicAdd(&summary[b * DM + ks * 512 + c2 * 64 + t], ssum * (1.f / 1024.f));
    }
  }
}

// ---------------------------------------------------------------------------
// K2 (merged): beta[b][s] = sigmoid(summary·Wbw[s] + Wbb[s]); softmax over n of
// the summed keys slabs -> ww_t[b][s][n] bf16. Grid 256 = one block per (b,s).
// ---------------------------------------------------------------------------
__launch_bounds__(256)
__global__ void k_bs(const float* __restrict__ summary, const float* __restrict__ Wbw,
                     const float* __restrict__ Wbb, const float* __restrict__ keys_part,
                     float* __restrict__ beta, unsigned short* __restrict__ ww_t) {
  __shared__ float wredb[4];
  __shared__ float wred[8];
  const int b = blockIdx.x >> 6, s = blockIdx.x & 63;
  const int t = threadIdx.x;
  // ---- beta dot ----
  {
    const float* sp = summary + b * DM + t * 16;
    const float* wp = Wbw + (size_t)s * DM + t * 16;
    float acc = 0.f;
#pragma unroll
    for (int j = 0; j < 4; ++j) {
      float4 a  = *(const float4*)(sp + j * 4);
      float4 w4 = *(const float4*)(wp + j * 4);
      acc += a.x * w4.x + a.y * w4.y + a.z * w4.z + a.w * w4.w;
    }
#pragma unroll
    for (int off = 32; off > 0; off >>= 1) acc += __shfl_xor(acc, off);
    if ((t & 63) == 0) wredb[t >> 6] = acc;
  }
  // ---- softmax ----
  const size_t base = ((size_t)(b * DSZ + s)) * NE + t * 4;
  float4 k = {0.f, 0.f, 0.f, 0.f};
#pragma unroll
  for (int sl = 0; sl < 8; ++sl) {
    float4 p = *(const float4*)&keys_part[(size_t)sl * (NB * DSZ * NE) + base];
    k.x += p.x; k.y += p.y; k.z += p.z; k.w += p.w;
  }
  float m = fmaxf(fmaxf(k.x, k.y), fmaxf(k.z, k.w));
#pragma unroll
  for (int off = 32; off > 0; off >>= 1) m = fmaxf(m, __shfl_xor(m, off));
  if ((t & 63) == 0) wred[t >> 6] = m;
  __syncthreads();
  const float M = fmaxf(fmaxf(wred[0], wred[1]), fmaxf(wred[2], wred[3]));
  float4 e = { expf(k.x - M), expf(k.y - M), expf(k.z - M), expf(k.w - M) };
  float ss = e.x + e.y + e.z + e.w;
#pragma unroll
  for (int off = 32; off > 0; off >>= 1) ss += __shfl_xor(ss, off);
  if ((t & 63) == 0) wred[4 + (t >> 6)] = ss;
  __syncthreads();
  const float inv = 1.f / (wred[4] + wred[5] + wred[6] + wred[7]);
  ushort4 o = { (unsigned short)f2bf(e.x * inv), (unsigned short)f2bf(e.y * inv),
                (unsigned short)f2bf(e.z * inv), (unsigned short)f2bf(e.w * inv) };
  *(ushort4*)&ww_t[((size_t)(b * DSZ + s)) * NE + t * 4] = o;
  if (t == 0) {
    float x = wredb[0] + wredb[1] + wredb[2] + wredb[3] + Wbb[s];
    beta[b * DSZ + s] = 1.f / (1.f + expf(-x));
  }
}

// ---------------------------------------------------------------------------
// K3: new_state^T[b][d][s] (bf16) = beta[b][s]*state[b][s][d] + sum_n ww[b][s][n]*ev[b][n][d]
// Grid 512 = B(4) x DT(128, 32-wide d tiles). Block 256 = 4 waves.
// ---------------------------------------------------------------------------
__launch_bounds__(256)
__global__ void k_update(const unsigned short* __restrict__ evb, const float* __restrict__ state,
                         const float* __restrict__ beta, const unsigned short* __restrict__ ww_t,
                         unsigned short* __restrict__ ns_t) {
  __shared__ __align__(16) unsigned short Aw[2][64][72];  // [s][n]
  __shared__ __align__(16) unsigned short Bt[2][32][72];  // [d][n]
  const int bid = blockIdx.x;
  const int dt = bid & 127, b = bid >> 7;
  const int d0 = dt * 32;
  const int t = threadIdx.x;
  const int w = t >> 6, m15 = t & 15, quad = (t & 63) >> 4;
  const int rowS = t >> 2, seg = (t & 3) * 16;
  const int npair = (t & 31) * 2, dquad = (t >> 5) * 4;

  f32x4 acc[2];
#pragma unroll
  for (int i = 0; i < 2; ++i) acc[i] = (f32x4){0.f, 0.f, 0.f, 0.f};

  const unsigned short* wp = ww_t + ((size_t)(b * DSZ + rowS)) * NE + seg;
  const unsigned short* ep = evb + ((size_t)(b * NE + npair)) * DM + d0 + dquad;

  uint4 wa = *(const uint4*)(wp), wb = *(const uint4*)(wp + 8);
  uint2 r0 = *(const uint2*)(ep), r1 = *(const uint2*)(ep + DM);
  int cur = 0;
  for (int ch = 0; ch < 16; ++ch) {
    *(uint4*)&Aw[cur][rowS][seg]     = wa;
    *(uint4*)&Aw[cur][rowS][seg + 8] = wb;
    // Bt[d][n] pairs: low = ev[n][d], high = ev[n+1][d]
    *(unsigned*)&Bt[cur][dquad + 0][npair] = (r0.x & 0xffffu) | (r1.x << 16);
    *(unsigned*)&Bt[cur][dquad + 1][npair] = (r0.x >> 16) | (r1.x & 0xffff0000u);
    *(unsigned*)&Bt[cur][dquad + 2][npair] = (r0.y & 0xffffu) | (r1.y << 16);
    *(unsigned*)&Bt[cur][dquad + 3][npair] = (r0.y >> 16) | (r1.y & 0xffff0000u);
    __syncthreads();
    if (ch < 15) {
      wp += 64; ep += (size_t)64 * DM;
      wa = *(const uint4*)(wp); wb = *(const uint4*)(wp + 8);
      r0 = *(const uint2*)(ep); r1 = *(const uint2*)(ep + DM);
    }
#pragma unroll
    for (int kk = 0; kk < 2; ++kk) {
      bf16x8 af = *(const bf16x8*)&Aw[cur][w * 16 + m15][kk * 32 + quad * 8];
#pragma unroll
      for (int tn = 0; tn < 2; ++tn) {
        bf16x8 bfr = *(const bf16x8*)&Bt[cur][tn * 16 + m15][kk * 32 + quad * 8];
        acc[tn] = __builtin_amdgcn_mfma_f32_16x16x32_bf16(af, bfr, acc[tn], 0, 0, 0);
      }
    }
    cur ^= 1;
  }
  // D frag: row = s = w*16+quad*4+r, col = d = d0+tn*16+m15. Store transposed [d][s].
  const int sbase = w * 16 + quad * 4;
#pragma unroll
  for (int tn = 0; tn < 2; ++tn) {
    const int d = d0 + tn * 16 + m15;
    float v[4];
#pragma unroll
    for (int r = 0; r < 4; ++r) {
      const int s = sbase + r;
      v[r] = beta[b * DSZ + s] * state[((size_t)(b * DSZ + s)) * DM + d] + acc[tn][r];
    }
    ushort4 o = { (unsigned short)f2bf(v[0]), (unsigned short)f2bf(v[1]),
                  (unsigned short)f2bf(v[2]), (unsigned short)f2bf(v[3]) };
    *(ushort4*)&ns_t[((size_t)(b * DM + d)) * DSZ + sbase] = o;
  }
}

// ---------------------------------------------------------------------------
// K4: q_part[ks][b][l][s] = partial current·W_query; fused gate logit partials.
// Grid 512 = B x MT(32) x KS(4). OPERAND-SWAPPED MFMA: first operand = Wq tile
// (rows = s), second = cur tile (rows = l) -> lane holds 4 consecutive s for one
// l -> float4 stores (4 instead of 16 scalar dwords).
// ---------------------------------------------------------------------------
__launch_bounds__(256)
__global__ void k_q(const float* __restrict__ cur_, const float* __restrict__ Wq,
                    const float* __restrict__ gate_w,
                    float* __restrict__ q_part, float* __restrict__ gate_acc) {
  __shared__ __align__(16) unsigned short As[2][64][72];
  __shared__ __align__(16) unsigned short Bs[2][64][72];
  __shared__ float gwAll[1024];
  __shared__ float gred[256];
  const int bid = blockIdx.x;
  const int ks = bid & 3, mt = (bid >> 2) & 31, b = bid >> 7;
  const int l0 = mt * 64;
  const int t = threadIdx.x;
  const int w = t >> 6, m15 = t & 15, quad = (t & 63) >> 4;
  const int rowS = t >> 2, seg = (t & 3) * 16;

  f32x4 acc[4];
#pragma unroll
  for (int i = 0; i < 4; ++i) acc[i] = (f32x4){0.f, 0.f, 0.f, 0.f};
  float gpart = 0.f;

  // hoist the whole gate_w K-slab once (4 KB)
  *(float4*)&gwAll[t * 4] = *(const float4*)(gate_w + ks * 1024 + t * 4);

  const float* ap = cur_ + ((size_t)(b * SQ + l0 + rowS)) * DM + ks * 1024 + seg;
  const float* bp = Wq + (size_t)rowS * DM + ks * 1024 + seg;

  float4 a0, a1, a2, a3, b0, b1, b2, b3;
  load8(ap, bp, a0, a1, a2, a3, b0, b1, b2, b3);
  int cur = 0;
  for (int ch = 0; ch < 16; ++ch) {
    *(uint4*)&As[cur][rowS][seg]     = (uint4){ pack2(a0.x,a0.y), pack2(a0.z,a0.w), pack2(a1.x,a1.y), pack2(a1.z,a1.w) };
    *(uint4*)&As[cur][rowS][seg + 8] = (uint4){ pack2(a2.x,a2.y), pack2(a2.z,a2.w), pack2(a3.x,a3.y), pack2(a3.z,a3.w) };
    *(uint4*)&Bs[cur][rowS][seg]     = (uint4){ pack2(b0.x,b0.y), pack2(b0.z,b0.w), pack2(b1.x,b1.y), pack2(b1.z,b1.w) };
    *(uint4*)&Bs[cur][rowS][seg + 8] = (uint4){ pack2(b2.x,b2.y), pack2(b2.z,b2.w), pack2(b3.x,b3.y), pack2(b3.z,b3.w) };
    __syncthreads();
    {  // gate dot on the still-live a-regs (gwAll valid after first barrier)
      const float* g = &gwAll[ch * 64 + seg];
      gpart += a0.x*g[0]  + a0.y*g[1]  + a0.z*g[2]  + a0.w*g[3]
             + a1.x*g[4]  + a1.y*g[5]  + a1.z*g[6]  + a1.w*g[7]
             + a2.x*g[8]  + a2.y*g[9]  + a2.z*g[10] + a2.w*g[11]
             + a3.x*g[12] + a3.y*g[13] + a3.z*g[14] + a3.w*g[15];
    }
    if (ch < 15) {
      ap += 64; bp += 64;
      load8(ap, bp, a0, a1, a2, a3, b0, b1, b2, b3);
    }
#pragma unroll
    for (int kk = 0; kk < 2; ++kk) {
      bf16x8 af = *(const bf16x8*)&Bs[cur][w * 16 + m15][kk * 32 + quad * 8];   // Wq rows = s
#pragma unroll
      for (int tn = 0; tn < 4; ++tn) {
        bf16x8 bfr = *(const bf16x8*)&As[cur][tn * 16 + m15][kk * 32 + quad * 8];  // cur rows = l
        acc[tn] = __builtin_amdgcn_mfma_f32_16x16x32_bf16(af, bfr, acc[tn], 0, 0, 0);
      }
    }
    cur ^= 1;
  }
  // D frag: row = s = w*16+quad*4+r, col = l = tn*16+m15 -> float4 store over s.
  const int srow = w * 16 + quad * 4;
  const int SL = NB * SQ * DSZ;
#pragma unroll
  for (int tn = 0; tn < 4; ++tn) {
    const int l = l0 + tn * 16 + m15;
    float4 v = { acc[tn][0], acc[tn][1], acc[tn][2], acc[tn][3] };
    *(float4*)&q_part[(size_t)ks * SL + ((size_t)(b * SQ + l)) * DSZ + srow] = v;
  }
  // gate partial reduce: row index = t>>2, partials at t = 4r..4r+3
  gred[t] = gpart;
  __syncthreads();
  if (t < 64) {
    float tot = gred[4 * t] + gred[4 * t + 1] + gred[4 * t + 2] + gred[4 * t + 3];
    atomicAdd(&gate_acc[b * SQ + l0 + t], tot);
  }
}

// ---------------------------------------------------------------------------
// K5: out[b][l][d] = sigmoid(gate_acc+gate_b) * sum_s q[l][s]*ns_t[d][s]
// Grid 2048 = B(4) x LT(32) x DS(16, 256-wide d). Block 256 = 4 waves;
// 8 blocks/CU -> whole kernel ~1 resident round. q-tile summed+packed ONCE,
// then 4 d-subtiles streamed. OPERAND-SWAPPED MFMA: first operand = ns (rows=d),
// second = q (rows=l) -> lane holds 4 consecutive d -> float4 out stores.
// ---------------------------------------------------------------------------
__launch_bounds__(256)
__global__ void k_out(const float* __restrict__ q_part, const unsigned short* __restrict__ ns_t,
                      const float* __restrict__ gate_acc, const float* __restrict__ gate_b,
                      float* __restrict__ out) {
  __shared__ __align__(16) unsigned short Qs[64][72];
  const int bid = blockIdx.x;
  const int dseg = bid & 15, lt = (bid >> 4) & 31, b = bid >> 9;
  const int dbase = dseg * 256, l0 = lt * 64;
  const int t = threadIdx.x;
  const int w = t >> 6, m15 = t & 15, quad = (t & 63) >> 4;
  const int rowS = t >> 2, seg = (t & 3) * 16;
  // phase 1: sum the 4 q_part slabs for this l-tile, pack to LDS (once per block)
  {
    const int SL = NB * SQ * DSZ;
    const float* qp = q_part + ((size_t)(b * SQ + l0 + rowS)) * DSZ + seg;
    float4 s0 = {0,0,0,0}, s1 = s0, s2 = s0, s3 = s0;
#pragma unroll
    for (int sl = 0; sl < 4; ++sl) {
      const float* p = qp + (size_t)sl * SL;
      float4 u0 = *(const float4*)(p);
      float4 u1 = *(const float4*)(p + 4);
      float4 u2 = *(const float4*)(p + 8);
      float4 u3 = *(const float4*)(p + 12);
      s0.x += u0.x; s0.y += u0.y; s0.z += u0.z; s0.w += u0.w;
      s1.x += u1.x; s1.y += u1.y; s1.z += u1.z; s1.w += u1.w;
      s2.x += u2.x; s2.y += u2.y; s2.z += u2.z; s2.w += u2.w;
      s3.x += u3.x; s3.y += u3.y; s3.z += u3.z; s3.w += u3.w;
    }
    *(uint4*)&Qs[rowS][seg]     = (uint4){ pack2(s0.x,s0.y), pack2(s0.z,s0.w), pack2(s1.x,s1.y), pack2(s1.z,s1.w) };
    *(uint4*)&Qs[rowS][seg + 8] = (uint4){ pack2(s2.x,s2.y), pack2(s2.z,s2.w), pack2(s3.x,s3.y), pack2(s3.z,s3.w) };
  }
  // gate for this thread's 4 l values (col = tn*16 + m15)
  const float gb = gate_b[0];
  float g[4];
#pragma unroll
  for (int tn = 0; tn < 4; ++tn)
    g[tn] = 1.f / (1.f + expf(-(gate_acc[b * SQ + l0 + tn * 16 + m15] + gb)));
  __syncthreads();
  // phase 2: stream 4 d-subtiles of 64
  for (int dsub = 0; dsub < 4; ++dsub) {
    const int d0 = dbase + dsub * 64;
    const int drow = d0 + w * 16 + m15;   // first-operand row = d
    f32x4 acc[4];
#pragma unroll
    for (int i = 0; i < 4; ++i) acc[i] = (f32x4){0.f, 0.f, 0.f, 0.f};
#pragma unroll
    for (int kk = 0; kk < 2; ++kk) {
      bf16x8 af = *(const bf16x8*)&ns_t[((size_t)(b * DM + drow)) * DSZ + kk * 32 + quad * 8];
#pragma unroll
      for (int tn = 0; tn < 4; ++tn) {
        bf16x8 bfr = *(const bf16x8*)&Qs[tn * 16 + m15][kk * 32 + quad * 8];
        acc[tn] = __builtin_amdgcn_mfma_f32_16x16x32_bf16(af, bfr, acc[tn], 0, 0, 0);
      }
    }
    // D frag: row = d = d0+w*16+quad*4+r, col = l = tn*16+m15 -> float4 store over d.
    const int dcol = d0 + w * 16 + quad * 4;
#pragma unroll
    for (int tn = 0; tn < 4; ++tn) {
      const int l = l0 + tn * 16 + m15;
      float4 v = { g[tn] * acc[tn][0], g[tn] * acc[tn][1],
                   g[tn] * acc[tn][2], g[tn] * acc[tn][3] };
      *(float4*)&out[((size_t)(b * SQ + l)) * DM + dcol] = v;
    }
  }
}

// ---------------------------------------------------------------------------
extern "C" void kernel_launch(void* const* d_in, const int* in_sizes, int n_in,
                              void* d_out, int out_size, void* d_ws, size_t ws_size,
                              hipStream_t stream) {
  const float* state   = (const float*)d_in[0];
  const float* evicted = (const float*)d_in[1];
  const float* current = (const float*)d_in[2];
  const float* Wkey    = (const float*)d_in[3];
  const float* Wbw     = (const float*)d_in[4];
  const float* Wbb     = (const float*)d_in[5];
  const float* Wq      = (const float*)d_in[6];
  const float* gate_w  = (const float*)d_in[7];
  const float* gate_b  = (const float*)d_in[8];
  float* out = (float*)d_out;

  // workspace layout (~51 MB total)
  float* f = (float*)d_ws;
  float* keys_part = f;                              // 8 * 262144 f  (8 MB)
  float* q_part    = keys_part + 8 * 262144;         // 4 * 524288 f  (8 MB)
  float* summary   = q_part + 4 * 524288;            // 16384 f
  float* gate_acc  = summary + 16384;                // 8192 f
  float* beta      = gate_acc + 8192;                // 256 f
  unsigned short* ww_t = (unsigned short*)(beta + 256);  // 262144 us (512 KB)
  unsigned short* ns_t = ww_t + 262144;                  // 1048576 us (2 MB)
  unsigned short* evb  = ns_t + 1048576;                 // 16777216 us (32 MB)

  // zero only the atomically-accumulated buffers (summary + gate_acc, contiguous)
  hipMemsetAsync(summary, 0, (16384 + 8192) * sizeof(float), stream);

  k_keys   <<<512,  256, 0, stream>>>(evicted, Wkey, keys_part, evb, summary);
  k_q      <<<512,  256, 0, stream>>>(current, Wq, gate_w, q_part, gate_acc);
  k_bs     <<<256,  256, 0, stream>>>(summary, Wbw, Wbb, keys_part, beta, ww_t);
  k_update <<<512,  256, 0, stream>>>(evb, state, beta, ww_t, ns_t);
  k_out    <<<2048, 256, 0, stream>>>(q_part, ns_t, gate_acc, gate_b, out);
}

// Round 6
// 351.995 us; speedup vs baseline: 1.1447x; 1.0060x over previous
//
#include <hip/hip_runtime.h>

// Problem constants
#define DM 4096   // d_model
#define DSZ 64    // d_state
#define NE 1024   // num evicted
#define SQ 2048   // seq len
#define NB 4      // batch

typedef __attribute__((ext_vector_type(8))) short bf16x8;
typedef __attribute__((ext_vector_type(4))) float f32x4;

// Single-instruction RNE fp32-pair -> packed bf16 (gfx950 v_cvt_pk_bf16_f32).
__device__ __forceinline__ unsigned pack2(float lo, float hi) {
  unsigned r;
  asm("v_cvt_pk_bf16_f32 %0, %1, %2" : "=v"(r) : "v"(lo), "v"(hi));
  return r;
}
__device__ __forceinline__ float bf2f(unsigned short h) {
  union { unsigned u; float f; } v; v.u = ((unsigned)h) << 16; return v.f;
}

__device__ __forceinline__ void load8(const float* __restrict__ ap, const float* __restrict__ bp,
                                      float4& a0, float4& a1, float4& a2, float4& a3,
                                      float4& b0, float4& b1, float4& b2, float4& b3) {
  a0 = *(const float4*)(ap);      a1 = *(const float4*)(ap + 4);
  a2 = *(const float4*)(ap + 8);  a3 = *(const float4*)(ap + 12);
  b0 = *(const float4*)(bp);      b1 = *(const float4*)(bp + 4);
  b2 = *(const float4*)(bp + 8);  b3 = *(const float4*)(bp + 12);
}

// ---------------------------------------------------------------------------
// K1 (fused): keys_part[ks][b][s][n] partials of evicted·W_key; ALSO writes
// evb = bf16(evicted) (reused by k_update) and spart[mt] summary partial slabs
// (non-atomic; k_bs sums the 16 slabs). Grid 512 = B(4) x MT(16) x KS(8).
// ---------------------------------------------------------------------------
__launch_bounds__(256)
__global__ void k_keys(const float* __restrict__ ev, const float* __restrict__ Wk,
                       float* __restrict__ keys_part, unsigned short* __restrict__ evb,
                       float* __restrict__ spart) {
  __shared__ __align__(16) unsigned short As[2][64][72];
  __shared__ __align__(16) unsigned short Bs[2][64][72];
  __shared__ float csum[8][4][64];  // per-chunk column partial sums (8 KB)
  const int bid = blockIdx.x;
  const int ks = bid & 7, mt = (bid >> 3) & 15, b = bid >> 7;
  const int n0 = mt * 64;
  const int t = threadIdx.x;
  const int w = t >> 6, m15 = t & 15, quad = (t & 63) >> 4;
  const int rowS = t >> 2, seg = (t & 3) * 16;
  const int ccol = t & 63, cgrp = t >> 6;

  f32x4 acc[4];
#pragma unroll
  for (int i = 0; i < 4; ++i) acc[i] = (f32x4){0.f, 0.f, 0.f, 0.f};

  const float* ap = ev + ((size_t)(b * NE + n0 + rowS)) * DM + ks * 512 + seg;
  const float* bp = Wk + (size_t)rowS * DM + ks * 512 + seg;
  unsigned short* evp = evb + ((size_t)(b * NE + n0 + rowS)) * DM + ks * 512 + seg;

  float4 a0, a1, a2, a3, b0, b1, b2, b3;
  load8(ap, bp, a0, a1, a2, a3, b0, b1, b2, b3);
  int cur = 0;
  for (int ch = 0; ch < 8; ++ch) {
    uint4 pa0 = { pack2(a0.x,a0.y), pack2(a0.z,a0.w), pack2(a1.x,a1.y), pack2(a1.z,a1.w) };
    uint4 pa1 = { pack2(a2.x,a2.y), pack2(a2.z,a2.w), pack2(a3.x,a3.y), pack2(a3.z,a3.w) };
    *(uint4*)&As[cur][rowS][seg]     = pa0;
    *(uint4*)&As[cur][rowS][seg + 8] = pa1;
    *(uint4*)&Bs[cur][rowS][seg]     = (uint4){ pack2(b0.x,b0.y), pack2(b0.z,b0.w), pack2(b1.x,b1.y), pack2(b1.z,b1.w) };
    *(uint4*)&Bs[cur][rowS][seg + 8] = (uint4){ pack2(b2.x,b2.y), pack2(b2.z,b2.w), pack2(b3.x,b3.y), pack2(b3.z,b3.w) };
    *(uint4*)(evp)     = pa0;   // evb write: same data, coalesced 32B/thread
    *(uint4*)(evp + 8) = pa1;
    __syncthreads();
    if (ch < 7) {  // prefetch next chunk; latency hides under MFMA below
      ap += 64; bp += 64; evp += 64;
      load8(ap, bp, a0, a1, a2, a3, b0, b1, b2, b3);
    }
    {  // column sums of this chunk's A-tile (for summary)
      float cs = 0.f;
#pragma unroll
      for (int r = 0; r < 16; ++r) cs += bf2f(As[cur][cgrp * 16 + r][ccol]);
      csum[ch][cgrp][ccol] = cs;
    }
#pragma unroll
    for (int kk = 0; kk < 2; ++kk) {
      bf16x8 af = *(const bf16x8*)&As[cur][w * 16 + m15][kk * 32 + quad * 8];
#pragma unroll
      for (int tn = 0; tn < 4; ++tn) {
        bf16x8 bfr = *(const bf16x8*)&Bs[cur][tn * 16 + m15][kk * 32 + quad * 8];
        acc[tn] = __builtin_amdgcn_mfma_f32_16x16x32_bf16(af, bfr, acc[tn], 0, 0, 0);
      }
    }
    cur ^= 1;
  }
  // D frag: row (= token n) = quad*4+r, col (= s) = m15. 4 consecutive n -> float4 store.
  const int n = n0 + w * 16 + quad * 4;
#pragma unroll
  for (int tn = 0; tn < 4; ++tn) {
    const int s = tn * 16 + m15;
    float4 v = { acc[tn][0], acc[tn][1], acc[tn][2], acc[tn][3] };
    *(float4*)&keys_part[(size_t)ks * (NB * DSZ * NE) + ((size_t)(b * DSZ + s)) * NE + n] = v;
  }
  // summary partial flush (non-atomic, unique (mt,b,ks,d) per block)
  __syncthreads();
  if (t < 64) {
#pragma unroll
    for (int c2 = 0; c2 < 8; ++c2) {
      float ssum = csum[c2][0][t] + csum[c2][1][t] + csum[c2][2][t] + csum[c2][3][t];
      spart[(size_t)mt * (NB * DM) + b * DM + ks * 512 + c2 * 64 + t] = ssum * (1.f / 1024.f);
    }
  }
}

// ---------------------------------------------------------------------------
// K2 (merged): beta[b][s] = sigmoid(sum_mt spart·Wbw[s] + Wbb[s]); softmax over
// n of the summed keys slabs -> ww_t[b][s][n] bf16. Grid 256 = one per (b,s).
// ---------------------------------------------------------------------------
__launch_bounds__(256)
__global__ void k_bs(const float* __restrict__ spart, const float* __restrict__ Wbw,
                     const float* __restrict__ Wbb, const float* __restrict__ keys_part,
                     float* __restrict__ beta, unsigned short* __restrict__ ww_t) {
  __shared__ float wredb[4];
  __shared__ float wred[8];
  const int b = blockIdx.x >> 6, s = blockIdx.x & 63;
  const int t = threadIdx.x;
  // ---- beta dot (sum the 16 summary slabs in fp32, then dot) ----
  {
    float4 sv0 = {0,0,0,0}, sv1 = sv0, sv2 = sv0, sv3 = sv0;
#pragma unroll
    for (int mt = 0; mt < 16; ++mt) {
      const float* pp = spart + (size_t)mt * (NB * DM) + b * DM + t * 16;
      float4 u0 = *(const float4*)(pp);
      float4 u1 = *(const float4*)(pp + 4);
      float4 u2 = *(const float4*)(pp + 8);
      float4 u3 = *(const float4*)(pp + 12);
      sv0.x += u0.x; sv0.y += u0.y; sv0.z += u0.z; sv0.w += u0.w;
      sv1.x += u1.x; sv1.y += u1.y; sv1.z += u1.z; sv1.w += u1.w;
      sv2.x += u2.x; sv2.y += u2.y; sv2.z += u2.z; sv2.w += u2.w;
      sv3.x += u3.x; sv3.y += u3.y; sv3.z += u3.z; sv3.w += u3.w;
    }
    const float* wp = Wbw + (size_t)s * DM + t * 16;
    float4 w0 = *(const float4*)(wp), w1 = *(const float4*)(wp + 4);
    float4 w2 = *(const float4*)(wp + 8), w3 = *(const float4*)(wp + 12);
    float acc = sv0.x*w0.x + sv0.y*w0.y + sv0.z*w0.z + sv0.w*w0.w
              + sv1.x*w1.x + sv1.y*w1.y + sv1.z*w1.z + sv1.w*w1.w
              + sv2.x*w2.x + sv2.y*w2.y + sv2.z*w2.z + sv2.w*w2.w
              + sv3.x*w3.x + sv3.y*w3.y + sv3.z*w3.z + sv3.w*w3.w;
#pragma unroll
    for (int off = 32; off > 0; off >>= 1) acc += __shfl_xor(acc, off);
    if ((t & 63) == 0) wredb[t >> 6] = acc;
  }
  // ---- softmax ----
  const size_t base = ((size_t)(b * DSZ + s)) * NE + t * 4;
  float4 k = {0.f, 0.f, 0.f, 0.f};
#pragma unroll
  for (int sl = 0; sl < 8; ++sl) {
    float4 p = *(const float4*)&keys_part[(size_t)sl * (NB * DSZ * NE) + base];
    k.x += p.x; k.y += p.y; k.z += p.z; k.w += p.w;
  }
  float m = fmaxf(fmaxf(k.x, k.y), fmaxf(k.z, k.w));
#pragma unroll
  for (int off = 32; off > 0; off >>= 1) m = fmaxf(m, __shfl_xor(m, off));
  if ((t & 63) == 0) wred[t >> 6] = m;
  __syncthreads();
  const float M = fmaxf(fmaxf(wred[0], wred[1]), fmaxf(wred[2], wred[3]));
  float4 e = { expf(k.x - M), expf(k.y - M), expf(k.z - M), expf(k.w - M) };
  float ss = e.x + e.y + e.z + e.w;
#pragma unroll
  for (int off = 32; off > 0; off >>= 1) ss += __shfl_xor(ss, off);
  if ((t & 63) == 0) wred[4 + (t >> 6)] = ss;
  __syncthreads();
  const float inv = 1.f / (wred[4] + wred[5] + wred[6] + wred[7]);
  uint2 o = { pack2(e.x * inv, e.y * inv), pack2(e.z * inv, e.w * inv) };
  *(uint2*)&ww_t[((size_t)(b * DSZ + s)) * NE + t * 4] = o;
  if (t == 0) {
    float x = wredb[0] + wredb[1] + wredb[2] + wredb[3] + Wbb[s];
    beta[b * DSZ + s] = 1.f / (1.f + expf(-x));
  }
}

// ---------------------------------------------------------------------------
// K3: new_state^T[b][d][s] (bf16) = beta[b][s]*state[b][s][d] + sum_n ww[b][s][n]*ev[b][n][d]
// Grid 512 = B(4) x DT(128, 32-wide d tiles). Block 256 = 4 waves.
// ---------------------------------------------------------------------------
__launch_bounds__(256)
__global__ void k_update(const unsigned short* __restrict__ evb, const float* __restrict__ state,
                         const float* __restrict__ beta, const unsigned short* __restrict__ ww_t,
                         unsigned short* __restrict__ ns_t) {
  __shared__ __align__(16) unsigned short Aw[2][64][72];  // [s][n]
  __shared__ __align__(16) unsigned short Bt[2][32][72];  // [d][n]
  const int bid = blockIdx.x;
  const int dt = bid & 127, b = bid >> 7;
  const int d0 = dt * 32;
  const int t = threadIdx.x;
  const int w = t >> 6, m15 = t & 15, quad = (t & 63) >> 4;
  const int rowS = t >> 2, seg = (t & 3) * 16;
  const int npair = (t & 31) * 2, dquad = (t >> 5) * 4;

  f32x4 acc[2];
#pragma unroll
  for (int i = 0; i < 2; ++i) acc[i] = (f32x4){0.f, 0.f, 0.f, 0.f};

  const unsigned short* wp = ww_t + ((size_t)(b * DSZ + rowS)) * NE + seg;
  const unsigned short* ep = evb + ((size_t)(b * NE + npair)) * DM + d0 + dquad;

  uint4 wa = *(const uint4*)(wp), wb = *(const uint4*)(wp + 8);
  uint2 r0 = *(const uint2*)(ep), r1 = *(const uint2*)(ep + DM);
  int cur = 0;
  for (int ch = 0; ch < 16; ++ch) {
    *(uint4*)&Aw[cur][rowS][seg]     = wa;
    *(uint4*)&Aw[cur][rowS][seg + 8] = wb;
    // Bt[d][n] pairs: low = ev[n][d], high = ev[n+1][d]
    *(unsigned*)&Bt[cur][dquad + 0][npair] = (r0.x & 0xffffu) | (r1.x << 16);
    *(unsigned*)&Bt[cur][dquad + 1][npair] = (r0.x >> 16) | (r1.x & 0xffff0000u);
    *(unsigned*)&Bt[cur][dquad + 2][npair] = (r0.y & 0xffffu) | (r1.y << 16);
    *(unsigned*)&Bt[cur][dquad + 3][npair] = (r0.y >> 16) | (r1.y & 0xffff0000u);
    __syncthreads();
    if (ch < 15) {
      wp += 64; ep += (size_t)64 * DM;
      wa = *(const uint4*)(wp); wb = *(const uint4*)(wp + 8);
      r0 = *(const uint2*)(ep); r1 = *(const uint2*)(ep + DM);
    }
#pragma unroll
    for (int kk = 0; kk < 2; ++kk) {
      bf16x8 af = *(const bf16x8*)&Aw[cur][w * 16 + m15][kk * 32 + quad * 8];
#pragma unroll
      for (int tn = 0; tn < 2; ++tn) {
        bf16x8 bfr = *(const bf16x8*)&Bt[cur][tn * 16 + m15][kk * 32 + quad * 8];
        acc[tn] = __builtin_amdgcn_mfma_f32_16x16x32_bf16(af, bfr, acc[tn], 0, 0, 0);
      }
    }
    cur ^= 1;
  }
  // D frag: row = s = w*16+quad*4+r, col = d = d0+tn*16+m15. Store transposed [d][s].
  const int sbase = w * 16 + quad * 4;
#pragma unroll
  for (int tn = 0; tn < 2; ++tn) {
    const int d = d0 + tn * 16 + m15;
    float v[4];
#pragma unroll
    for (int r = 0; r < 4; ++r) {
      const int s = sbase + r;
      v[r] = beta[b * DSZ + s] * state[((size_t)(b * DSZ + s)) * DM + d] + acc[tn][r];
    }
    uint2 o = { pack2(v[0], v[1]), pack2(v[2], v[3]) };
    *(uint2*)&ns_t[((size_t)(b * DM + d)) * DSZ + sbase] = o;
  }
}

// ---------------------------------------------------------------------------
// K4: q_part[ks][b][l][s] = partial current·W_query; gate logit partials to
// gate_part[ks] (non-atomic). Grid 512 = B x MT(32) x KS(4). Operand-swapped
// MFMA -> float4 q_part stores.
// ---------------------------------------------------------------------------
__launch_bounds__(256)
__global__ void k_q(const float* __restrict__ cur_, const float* __restrict__ Wq,
                    const float* __restrict__ gate_w,
                    float* __restrict__ q_part, float* __restrict__ gate_part) {
  __shared__ __align__(16) unsigned short As[2][64][72];
  __shared__ __align__(16) unsigned short Bs[2][64][72];
  __shared__ float gwAll[1024];
  __shared__ float gred[256];
  const int bid = blockIdx.x;
  const int ks = bid & 3, mt = (bid >> 2) & 31, b = bid >> 7;
  const int l0 = mt * 64;
  const int t = threadIdx.x;
  const int w = t >> 6, m15 = t & 15, quad = (t & 63) >> 4;
  const int rowS = t >> 2, seg = (t & 3) * 16;

  f32x4 acc[4];
#pragma unroll
  for (int i = 0; i < 4; ++i) acc[i] = (f32x4){0.f, 0.f, 0.f, 0.f};
  float gpart = 0.f;

  // hoist the whole gate_w K-slab once (4 KB)
  *(float4*)&gwAll[t * 4] = *(const float4*)(gate_w + ks * 1024 + t * 4);

  const float* ap = cur_ + ((size_t)(b * SQ + l0 + rowS)) * DM + ks * 1024 + seg;
  const float* bp = Wq + (size_t)rowS * DM + ks * 1024 + seg;

  float4 a0, a1, a2, a3, b0, b1, b2, b3;
  load8(ap, bp, a0, a1, a2, a3, b0, b1, b2, b3);
  int cur = 0;
  for (int ch = 0; ch < 16; ++ch) {
    *(uint4*)&As[cur][rowS][seg]     = (uint4){ pack2(a0.x,a0.y), pack2(a0.z,a0.w), pack2(a1.x,a1.y), pack2(a1.z,a1.w) };
    *(uint4*)&As[cur][rowS][seg + 8] = (uint4){ pack2(a2.x,a2.y), pack2(a2.z,a2.w), pack2(a3.x,a3.y), pack2(a3.z,a3.w) };
    *(uint4*)&Bs[cur][rowS][seg]     = (uint4){ pack2(b0.x,b0.y), pack2(b0.z,b0.w), pack2(b1.x,b1.y), pack2(b1.z,b1.w) };
    *(uint4*)&Bs[cur][rowS][seg + 8] = (uint4){ pack2(b2.x,b2.y), pack2(b2.z,b2.w), pack2(b3.x,b3.y), pack2(b3.z,b3.w) };
    __syncthreads();
    {  // gate dot on the still-live a-regs (gwAll valid after first barrier)
      const float* g = &gwAll[ch * 64 + seg];
      gpart += a0.x*g[0]  + a0.y*g[1]  + a0.z*g[2]  + a0.w*g[3]
             + a1.x*g[4]  + a1.y*g[5]  + a1.z*g[6]  + a1.w*g[7]
             + a2.x*g[8]  + a2.y*g[9]  + a2.z*g[10] + a2.w*g[11]
             + a3.x*g[12] + a3.y*g[13] + a3.z*g[14] + a3.w*g[15];
    }
    if (ch < 15) {
      ap += 64; bp += 64;
      load8(ap, bp, a0, a1, a2, a3, b0, b1, b2, b3);
    }
#pragma unroll
    for (int kk = 0; kk < 2; ++kk) {
      bf16x8 af = *(const bf16x8*)&Bs[cur][w * 16 + m15][kk * 32 + quad * 8];   // Wq rows = s
#pragma unroll
      for (int tn = 0; tn < 4; ++tn) {
        bf16x8 bfr = *(const bf16x8*)&As[cur][tn * 16 + m15][kk * 32 + quad * 8];  // cur rows = l
        acc[tn] = __builtin_amdgcn_mfma_f32_16x16x32_bf16(af, bfr, acc[tn], 0, 0, 0);
      }
    }
    cur ^= 1;
  }
  // D frag: row = s = w*16+quad*4+r, col = l = tn*16+m15 -> float4 store over s.
  const int srow = w * 16 + quad * 4;
  const int SL = NB * SQ * DSZ;
#pragma unroll
  for (int tn = 0; tn < 4; ++tn) {
    const int l = l0 + tn * 16 + m15;
    float4 v = { acc[tn][0], acc[tn][1], acc[tn][2], acc[tn][3] };
    *(float4*)&q_part[(size_t)ks * SL + ((size_t)(b * SQ + l)) * DSZ + srow] = v;
  }
  // gate partial reduce: row index = t>>2, partials at t = 4r..4r+3
  gred[t] = gpart;
  __syncthreads();
  if (t < 64) {
    float tot = gred[4 * t] + gred[4 * t + 1] + gred[4 * t + 2] + gred[4 * t + 3];
    gate_part[(size_t)ks * (NB * SQ) + b * SQ + l0 + t] = tot;
  }
}

// ---------------------------------------------------------------------------
// K5: out[b][l][d] = sigmoid(gate+gate_b) * sum_s q[l][s]*ns_t[d][s]
// Grid 2048 = B(4) x LT(32) x DS(16, 256-wide d). q-tile packed once; 4
// d-subtiles streamed; operand-swapped MFMA -> float4 out stores.
// ---------------------------------------------------------------------------
__launch_bounds__(256)
__global__ void k_out(const float* __restrict__ q_part, const unsigned short* __restrict__ ns_t,
                      const float* __restrict__ gate_part, const float* __restrict__ gate_b,
                      float* __restrict__ out) {
  __shared__ __align__(16) unsigned short Qs[64][72];
  const int bid = blockIdx.x;
  const int dseg = bid & 15, lt = (bid >> 4) & 31, b = bid >> 9;
  const int dbase = dseg * 256, l0 = lt * 64;
  const int t = threadIdx.x;
  const int w = t >> 6, m15 = t & 15, quad = (t & 63) >> 4;
  const int rowS = t >> 2, seg = (t & 3) * 16;
  const int SL = NB * SQ * DSZ;
  // phase 1: sum the 4 q_part slabs for this l-tile, pack to LDS (once per block)
  {
    const float* qp = q_part + ((size_t)(b * SQ + l0 + rowS)) * DSZ + seg;
    float4 s0 = {0,0,0,0}, s1 = s0, s2 = s0, s3 = s0;
#pragma unroll
    for (int sl = 0; sl < 4; ++sl) {
      const float* p = qp + (size_t)sl * SL;
      float4 u0 = *(const float4*)(p);
      float4 u1 = *(const float4*)(p + 4);
      float4 u2 = *(const float4*)(p + 8);
      float4 u3 = *(const float4*)(p + 12);
      s0.x += u0.x; s0.y += u0.y; s0.z += u0.z; s0.w += u0.w;
      s1.x += u1.x; s1.y += u1.y; s1.z += u1.z; s1.w += u1.w;
      s2.x += u2.x; s2.y += u2.y; s2.z += u2.z; s2.w += u2.w;
      s3.x += u3.x; s3.y += u3.y; s3.z += u3.z; s3.w += u3.w;
    }
    *(uint4*)&Qs[rowS][seg]     = (uint4){ pack2(s0.x,s0.y), pack2(s0.z,s0.w), pack2(s1.x,s1.y), pack2(s1.z,s1.w) };
    *(uint4*)&Qs[rowS][seg + 8] = (uint4){ pack2(s2.x,s2.y), pack2(s2.z,s2.w), pack2(s3.x,s3.y), pack2(s3.z,s3.w) };
  }
  // gate for this thread's 4 l values (col = tn*16 + m15): sum 4 partial slabs
  const float gb = gate_b[0];
  float g[4];
#pragma unroll
  for (int tn = 0; tn < 4; ++tn) {
    const int li = b * SQ + l0 + tn * 16 + m15;
    float x = gate_part[li] + gate_part[(size_t)(NB * SQ) + li]
            + gate_part[(size_t)2 * (NB * SQ) + li] + gate_part[(size_t)3 * (NB * SQ) + li] + gb;
    g[tn] = 1.f / (1.f + expf(-x));
  }
  __syncthreads();
  // phase 2: stream 4 d-subtiles of 64
  for (int dsub = 0; dsub < 4; ++dsub) {
    const int d0 = dbase + dsub * 64;
    const int drow = d0 + w * 16 + m15;   // first-operand row = d
    f32x4 acc[4];
#pragma unroll
    for (int i = 0; i < 4; ++i) acc[i] = (f32x4){0.f, 0.f, 0.f, 0.f};
#pragma unroll
    for (int kk = 0; kk < 2; ++kk) {
      bf16x8 af = *(const bf16x8*)&ns_t[((size_t)(b * DM + drow)) * DSZ + kk * 32 + quad * 8];
#pragma unroll
      for (int tn = 0; tn < 4; ++tn) {
        bf16x8 bfr = *(const bf16x8*)&Qs[tn * 16 + m15][kk * 32 + quad * 8];
        acc[tn] = __builtin_amdgcn_mfma_f32_16x16x32_bf16(af, bfr, acc[tn], 0, 0, 0);
      }
    }
    // D frag: row = d = d0+w*16+quad*4+r, col = l = tn*16+m15 -> float4 store over d.
    const int dcol = d0 + w * 16 + quad * 4;
#pragma unroll
    for (int tn = 0; tn < 4; ++tn) {
      const int l = l0 + tn * 16 + m15;
      float4 v = { g[tn] * acc[tn][0], g[tn] * acc[tn][1],
                   g[tn] * acc[tn][2], g[tn] * acc[tn][3] };
      *(float4*)&out[((size_t)(b * SQ + l)) * DM + dcol] = v;
    }
  }
}

// ---------------------------------------------------------------------------
extern "C" void kernel_launch(void* const* d_in, const int* in_sizes, int n_in,
                              void* d_out, int out_size, void* d_ws, size_t ws_size,
                              hipStream_t stream) {
  const float* state   = (const float*)d_in[0];
  const float* evicted = (const float*)d_in[1];
  const float* current = (const float*)d_in[2];
  const float* Wkey    = (const float*)d_in[3];
  const float* Wbw     = (const float*)d_in[4];
  const float* Wbb     = (const float*)d_in[5];
  const float* Wq      = (const float*)d_in[6];
  const float* gate_w  = (const float*)d_in[7];
  const float* gate_b  = (const float*)d_in[8];
  float* out = (float*)d_out;

  // workspace layout (~53 MB total); no memset needed (all partial slabs
  // are written non-atomically before being read).
  float* f = (float*)d_ws;
  float* keys_part = f;                              // 8 * 262144 f  (8 MB)
  float* q_part    = keys_part + 8 * 262144;         // 4 * 524288 f  (8 MB)
  float* spart     = q_part + 4 * 524288;            // 16 * 16384 f  (1 MB)
  float* gate_part = spart + 16 * 16384;             // 4 * 8192 f    (128 KB)
  float* beta      = gate_part + 4 * 8192;           // 256 f
  unsigned short* ww_t = (unsigned short*)(beta + 256);  // 262144 us (512 KB)
  unsigned short* ns_t = ww_t + 262144;                  // 1048576 us (2 MB)
  unsigned short* evb  = ns_t + 1048576;                 // 16777216 us (32 MB)

  k_keys   <<<512,  256, 0, stream>>>(evicted, Wkey, keys_part, evb, spart);
  k_q      <<<512,  256, 0, stream>>>(current, Wq, gate_w, q_part, gate_part);
  k_bs     <<<256,  256, 0, stream>>>(spart, Wbw, Wbb, keys_part, beta, ww_t);
  k_update <<<512,  256, 0, stream>>>(evb, state, beta, ww_t, ns_t);
  k_out    <<<2048, 256, 0, stream>>>(q_part, ns_t, gate_part, gate_b, out);
}